// Round 16
// baseline (256.713 us; speedup 1.0000x reference)
//
#include <hip/hip_runtime.h>
#include <hip/hip_bf16.h>

// d_out is FLOAT32. h_pen = first N*256 f32, h = next N*128 f32.

using bf16 = __hip_bfloat16;

typedef __attribute__((ext_vector_type(8))) short bf16x8;
typedef __attribute__((ext_vector_type(4))) short short4v;
typedef __attribute__((ext_vector_type(4))) float f32x4;
typedef __attribute__((ext_vector_type(2))) float f32x2;
typedef __attribute__((ext_vector_type(2))) unsigned int uint2v;

__device__ __forceinline__ float u2f(unsigned u) { union { float f; unsigned u; } c; c.u = u; return c.f; }
__device__ __forceinline__ unsigned f2u(float x) { union { float f; unsigned u; } c; c.f = x; return c.u; }
__device__ __forceinline__ short bfbits(float x) {
  unsigned xu = f2u(x);
  return (short)((xu + 0x7FFF + ((xu >> 16) & 1)) >> 16);
}

// ============================ CSR build (dst-sorted) ============================
__global__ void hist_kernel(const int* __restrict__ ei, int E, int N, int* __restrict__ cnt) {
  int e = blockIdx.x * 256 + threadIdx.x;
  if (e >= E + N) return;
  int dst = (e < E) ? ei[E + e] : (e - E);
  atomicAdd(&cnt[dst], 1);
}

__global__ __launch_bounds__(1024) void scan_kernel(const int* __restrict__ cnt,
                                                    int* __restrict__ row_start, int N) {
  __shared__ int part[1024];
  int t = threadIdx.x;
  int chunk = (N + 1023) / 1024;
  int lo = t * chunk; if (lo > N) lo = N;
  int hi = lo + chunk; if (hi > N) hi = N;
  int s = 0;
  for (int i = lo; i < hi; ++i) s += cnt[i];
  part[t] = s;
  __syncthreads();
  for (int off = 1; off < 1024; off <<= 1) {
    int add = (t >= off) ? part[t - off] : 0;
    __syncthreads();
    part[t] += add;
    __syncthreads();
  }
  int run = part[t] - s;
  for (int i = lo; i < hi; ++i) { row_start[i] = run; run += cnt[i]; }
  if (t == 1023) row_start[N] = part[1023];
}

__global__ void scatter_kernel(const int* __restrict__ ei, int E, int N,
                               const int* __restrict__ row_start, int* __restrict__ cursor,
                               int* __restrict__ csr_src) {
  int e = blockIdx.x * 256 + threadIdx.x;
  if (e >= E + N) return;
  int src, dst;
  if (e < E) { src = ei[e]; dst = ei[E + e]; }
  else       { src = e - E; dst = e - E; }
  int pos = atomicAdd(&cursor[dst], 1);
  csr_src[row_start[dst] + pos] = src;
}

// ============================ f32 -> bf16 hi/lo presplit ============================
__global__ void split_kernel(const float* __restrict__ in, unsigned short* __restrict__ hi,
                             unsigned short* __restrict__ lo, long long n4) {
  long long i = (long long)blockIdx.x * 256 + threadIdx.x;
  if (i >= n4) return;
  f32x4 v = *(const f32x4*)(in + i * 4);
  short4v h, l;
#pragma unroll
  for (int k = 0; k < 4; ++k) {
    short hb = bfbits(v[k]);
    h[k] = hb;
    l[k] = bfbits(v[k] - u2f(((unsigned)(unsigned short)hb) << 16));
  }
  *(short4v*)(hi + i * 4) = h;
  *(short4v*)(lo + i * 4) = l;
}

// ============================ MFMA GEMM: C = A * B^T (+ bf16 mirror) ============================
// B always from presplit hi/lo bf16 buffers (pure copy staging).
// A: ASPLIT=true -> f32, split in-kernel (layer 0); else presplit hi/lo (layers 1-2).
#define LDP 40  // LDS pitch in shorts (80B: 16B-aligned, breaks pow2 stride)

__device__ __forceinline__ bf16x8 make_frag(const short* S, int row, int g) {
  short4v klo = *(const short4v*)&S[row * LDP + g * 4];
  short4v khi = *(const short4v*)&S[row * LDP + 16 + g * 4];
  bf16x8 r;
#pragma unroll
  for (int i = 0; i < 4; ++i) { r[i] = klo[i]; r[i + 4] = khi[i]; }
  return r;
}

template <bool ASPLIT>
__global__ __launch_bounds__(256) void gemm_mfma(const float* __restrict__ Af,
                                                 const unsigned short* __restrict__ Ahg,
                                                 const unsigned short* __restrict__ Alg,
                                                 const unsigned short* __restrict__ Bhg,
                                                 const unsigned short* __restrict__ Blg,
                                                 float* __restrict__ C,
                                                 unsigned short* __restrict__ C16,
                                                 int M, int Nn, int K, int NB) {
  // XCD-aware: same-bm blocks differ by 8 in id -> same XCD -> A panel L2 reuse.
  int id = blockIdx.x;
  int r8 = id & 7;
  int q  = id >> 3;
  int bn = q % NB;
  int bm = r8 + 8 * (q / NB);
  if (bm * 64 >= M) return;

  __shared__ short Ah[64 * LDP];
  __shared__ short Al[64 * LDP];
  __shared__ short Bh[64 * LDP];
  __shared__ short Bl[64 * LDP];
  int t = threadIdx.x;
  int w = t >> 6, l = t & 63;
  int g = l >> 4, lr = l & 15;

  f32x4 acc[4];
#pragma unroll
  for (int j = 0; j < 4; ++j) acc[j] = (f32x4)(0.f);

  int srow = t >> 2, sseg = t & 3;          // 64 rows x 4 segments x 8 elems
  int gm = bm * 64 + srow;
  int gn = bn * 64 + srow;                  // Nn multiple of 64

  for (int kt = 0; kt < K; kt += 32) {
    __syncthreads();
    // ---- stage B: pure 16B copies from presplit buffers ----
    {
      size_t boff = (size_t)gn * K + kt + sseg * 8;
      int4 vh = *(const int4*)(Bhg + boff);
      int4 vl = *(const int4*)(Blg + boff);
      *(int4*)&Bh[srow * LDP + sseg * 8] = vh;
      *(int4*)&Bl[srow * LDP + sseg * 8] = vl;
    }
    // ---- stage A ----
    if constexpr (ASPLIT) {
      f32x4 v0 = (f32x4)(0.f), v1 = (f32x4)(0.f);
      if (gm < M) {
        const float* Arow = Af + (size_t)gm * K + kt + sseg * 8;
        v0 = *(const f32x4*)Arow;
        v1 = *(const f32x4*)(Arow + 4);
      }
      short4v h0, l0, h1, l1;
#pragma unroll
      for (int i = 0; i < 4; ++i) {
        short hb0 = bfbits(v0[i]);
        l0[i] = bfbits(v0[i] - u2f(((unsigned)(unsigned short)hb0) << 16));
        h0[i] = hb0;
        short hb1 = bfbits(v1[i]);
        l1[i] = bfbits(v1[i] - u2f(((unsigned)(unsigned short)hb1) << 16));
        h1[i] = hb1;
      }
      *(short4v*)&Ah[srow * LDP + sseg * 8]     = h0;
      *(short4v*)&Ah[srow * LDP + sseg * 8 + 4] = h1;
      *(short4v*)&Al[srow * LDP + sseg * 8]     = l0;
      *(short4v*)&Al[srow * LDP + sseg * 8 + 4] = l1;
    } else {
      int4 vh = make_int4(0, 0, 0, 0), vl = make_int4(0, 0, 0, 0);
      if (gm < M) {
        size_t aoff = (size_t)gm * K + kt + sseg * 8;
        vh = *(const int4*)(Ahg + aoff);
        vl = *(const int4*)(Alg + aoff);
      }
      *(int4*)&Ah[srow * LDP + sseg * 8] = vh;
      *(int4*)&Al[srow * LDP + sseg * 8] = vl;
    }
    __syncthreads();

    int arow = w * 16 + lr;
    bf16x8 ah = make_frag(Ah, arow, g);
    bf16x8 al = make_frag(Al, arow, g);
#pragma unroll
    for (int j = 0; j < 4; ++j) {
      int brow = j * 16 + lr;
      bf16x8 bh = make_frag(Bh, brow, g);
      bf16x8 bl = make_frag(Bl, brow, g);
      acc[j] = __builtin_amdgcn_mfma_f32_16x16x32_bf16(ah, bh, acc[j], 0, 0, 0);
      acc[j] = __builtin_amdgcn_mfma_f32_16x16x32_bf16(al, bh, acc[j], 0, 0, 0);
      acc[j] = __builtin_amdgcn_mfma_f32_16x16x32_bf16(ah, bl, acc[j], 0, 0, 0);
    }
  }

  // C/D layout (HW-verified m89): col = lane&15, row = (lane>>4)*4 + reg
#pragma unroll
  for (int j = 0; j < 4; ++j) {
#pragma unroll
    for (int r = 0; r < 4; ++r) {
      int row = bm * 64 + w * 16 + g * 4 + r;
      int col = bn * 64 + j * 16 + lr;
      if (row < M) {
        float v = acc[j][r];
        C[(size_t)row * Nn + col] = v;
        C16[(size_t)row * Nn + col] = (unsigned short)bfbits(v);
      }
    }
  }
}

// ============================ alpha projections: one wave per node ============================
template <int H, int C>
__global__ __launch_bounds__(64) void alpha_kernel(const float* __restrict__ Hb,
                                                   const float* __restrict__ a_src,
                                                   const float* __restrict__ a_dst,
                                                   float* __restrict__ as_,
                                                   float* __restrict__ ad_, int N) {
  constexpr int HC = H * C;
  constexpr int EPL = HC / 64;
  constexpr int LPH = 64 / H;
  int n = blockIdx.x;
  int l = threadIdx.x;
  const float* row = Hb + (size_t)n * HC + l * EPL;
  float s1 = 0.f, s2 = 0.f;
  if constexpr (EPL == 4) {
    f32x4 v = *(const f32x4*)row;
    f32x4 a1 = *(const f32x4*)(a_src + l * 4);
    f32x4 a2 = *(const f32x4*)(a_dst + l * 4);
#pragma unroll
    for (int k = 0; k < 4; ++k) { s1 += v[k] * a1[k]; s2 += v[k] * a2[k]; }
  } else {
    f32x2 v = *(const f32x2*)row;
    f32x2 a1 = *(const f32x2*)(a_src + l * 2);
    f32x2 a2 = *(const f32x2*)(a_dst + l * 2);
#pragma unroll
    for (int k = 0; k < 2; ++k) { s1 += v[k] * a1[k]; s2 += v[k] * a2[k]; }
  }
#pragma unroll
  for (int mask = 1; mask < LPH; mask <<= 1) {
    s1 += __shfl_xor(s1, mask);
    s2 += __shfl_xor(s2, mask);
  }
  if ((l & (LPH - 1)) == 0) {
    int h = l / LPH;
    as_[n * H + h] = s1;
    ad_[n * H + h] = s2;
  }
}

// ============================ softmax + aggregate (bf16 gather, 2-way unroll) ============================
// Outputs: optional f32 (d_out), optional bf16 hi/lo split (next layer's GEMM A operand).
template <int H, int C, bool RELU>
__global__ __launch_bounds__(64) void agg_kernel(const unsigned short* __restrict__ Hb16,
                                                 const float* __restrict__ as_,
                                                 const float* __restrict__ ad_,
                                                 const int* __restrict__ row_start,
                                                 const int* __restrict__ csr_src,
                                                 const float* __restrict__ bias,
                                                 float* __restrict__ out_f,
                                                 unsigned short* __restrict__ out_h,
                                                 unsigned short* __restrict__ out_l,
                                                 int N) {
  int n = blockIdx.x;
  if (n >= N) return;
  int l = threadIdx.x;
  int s = row_start[n], e = row_start[n + 1];

  constexpr int LPH = 64 / H;
  constexpr int CPL = C / LPH;
  constexpr int HC = H * C;
  int h2 = l / LPH;
  int cb = (l % LPH) * CPL;
  float ad2 = ad_[n * H + h2];

  float acc[CPL];
#pragma unroll
  for (int c = 0; c < CPL; ++c) acc[c] = 0.f;
  float denom = 0.f;

  int j = s;
  for (; j + 1 < e; j += 2) {
    int s0 = csr_src[j], s1v = csr_src[j + 1];
    float x0 = as_[s0 * H + h2] + ad2;
    float x1 = as_[s1v * H + h2] + ad2;
    x0 = x0 > 0.f ? x0 : 0.2f * x0;
    x1 = x1 > 0.f ? x1 : 0.2f * x1;
    float p0 = __expf(x0), p1 = __expf(x1);
    denom += p0 + p1;
    const unsigned short* hp0 = Hb16 + (size_t)s0 * HC + h2 * C + cb;
    const unsigned short* hp1 = Hb16 + (size_t)s1v * HC + h2 * C + cb;
    if constexpr (CPL == 4) {
      uint2v u0 = *(const uint2v*)hp0;
      uint2v u1 = *(const uint2v*)hp1;
#pragma unroll
      for (int c = 0; c < 2; ++c) {
        acc[2 * c]     += p0 * u2f(u0[c] << 16)         + p1 * u2f(u1[c] << 16);
        acc[2 * c + 1] += p0 * u2f(u0[c] & 0xFFFF0000u) + p1 * u2f(u1[c] & 0xFFFF0000u);
      }
    } else {
      unsigned u0 = *(const unsigned*)hp0;
      unsigned u1 = *(const unsigned*)hp1;
      acc[0] += p0 * u2f(u0 << 16)         + p1 * u2f(u1 << 16);
      acc[1] += p0 * u2f(u0 & 0xFFFF0000u) + p1 * u2f(u1 & 0xFFFF0000u);
    }
  }
  if (j < e) {
    int s0 = csr_src[j];
    float x0 = as_[s0 * H + h2] + ad2;
    x0 = x0 > 0.f ? x0 : 0.2f * x0;
    float p0 = __expf(x0);
    denom += p0;
    const unsigned short* hp0 = Hb16 + (size_t)s0 * HC + h2 * C + cb;
    if constexpr (CPL == 4) {
      uint2v u0 = *(const uint2v*)hp0;
#pragma unroll
      for (int c = 0; c < 2; ++c) {
        acc[2 * c]     += p0 * u2f(u0[c] << 16);
        acc[2 * c + 1] += p0 * u2f(u0[c] & 0xFFFF0000u);
      }
    } else {
      unsigned u0 = *(const unsigned*)hp0;
      acc[0] += p0 * u2f(u0 << 16);
      acc[1] += p0 * u2f(u0 & 0xFFFF0000u);
    }
  }

  float inv = 1.f / (denom + 1e-16f);
#pragma unroll
  for (int c = 0; c < CPL; ++c) {
    float v = acc[c] * inv + bias[h2 * C + cb + c];
    if (RELU) v = fmaxf(v, 0.f);
    size_t oi = (size_t)n * HC + h2 * C + cb + c;
    if (out_f) out_f[oi] = v;
    if (out_h) {
      short hb = bfbits(v);
      out_h[oi] = (unsigned short)hb;
      out_l[oi] = (unsigned short)bfbits(v - u2f(((unsigned)(unsigned short)hb) << 16));
    }
  }
}

// ============================ launch ============================
extern "C" void kernel_launch(void* const* d_in, const int* in_sizes, int n_in,
                              void* d_out, int out_size, void* d_ws, size_t ws_size,
                              hipStream_t stream) {
  const float* x    = (const float*)d_in[0];
  const int*   ei   = (const int*)d_in[1];
  const float* W0   = (const float*)d_in[2];
  const float* asr0 = (const float*)d_in[3];
  const float* adt0 = (const float*)d_in[4];
  const float* b0   = (const float*)d_in[5];
  const float* W1   = (const float*)d_in[6];
  const float* asr1 = (const float*)d_in[7];
  const float* adt1 = (const float*)d_in[8];
  const float* b1   = (const float*)d_in[9];
  const float* W2   = (const float*)d_in[10];
  const float* asr2 = (const float*)d_in[11];
  const float* adt2 = (const float*)d_in[12];
  const float* b2   = (const float*)d_in[13];

  const int FIN = 512, HID = 256, OUTC = 128;
  int N = in_sizes[0] / FIN;          // 20000
  int E = in_sizes[1] / 2;            // 320000
  int Etot = E + N;

  char* ws = (char*)d_ws;
  size_t off = 0;
  auto alloc = [&](size_t bytes) -> void* {
    void* p = ws + off;
    off = (off + bytes + 255) & ~(size_t)255;
    return p;
  };
  int* cnt       = (int*)alloc((size_t)N * 4);
  int* cursor    = (int*)alloc((size_t)N * 4);
  int* row_start = (int*)alloc((size_t)(N + 1) * 4);
  int* csr_src   = (int*)alloc((size_t)Etot * 4);
  float* as_     = (float*)alloc((size_t)N * 8 * 4);
  float* ad_     = (float*)alloc((size_t)N * 8 * 4);
  float* Hb      = (float*)alloc((size_t)N * HID * 4);            // GEMM out f32 (alpha input)
  unsigned short* Hb16  = (unsigned short*)alloc((size_t)N * HID * 2);  // GEMM out bf16 (agg gather)
  unsigned short* act_h = (unsigned short*)alloc((size_t)N * HID * 2);  // L0 out split
  unsigned short* act_l = (unsigned short*)alloc((size_t)N * HID * 2);
  unsigned short* h_h   = (unsigned short*)alloc((size_t)N * HID * 2);  // L1 out split
  unsigned short* h_l   = (unsigned short*)alloc((size_t)N * HID * 2);
  unsigned short* W0h = (unsigned short*)alloc((size_t)HID * FIN * 2);
  unsigned short* W0l = (unsigned short*)alloc((size_t)HID * FIN * 2);
  unsigned short* W1h = (unsigned short*)alloc((size_t)HID * HID * 2);
  unsigned short* W1l = (unsigned short*)alloc((size_t)HID * HID * 2);
  unsigned short* W2h = (unsigned short*)alloc((size_t)OUTC * HID * 2);
  unsigned short* W2l = (unsigned short*)alloc((size_t)OUTC * HID * 2);

  float* hpen = (float*)d_out;                       // [N, 256] f32
  float* out2 = (float*)d_out + (size_t)N * HID;     // [N, 128] f32

  // ---- presplit weights (once) ----
  long long w0n4 = (long long)HID * FIN / 4, w1n4 = (long long)HID * HID / 4,
            w2n4 = (long long)OUTC * HID / 4;
  split_kernel<<<(int)((w0n4 + 255) / 256), 256, 0, stream>>>(W0, W0h, W0l, w0n4);
  split_kernel<<<(int)((w1n4 + 255) / 256), 256, 0, stream>>>(W1, W1h, W1l, w1n4);
  split_kernel<<<(int)((w2n4 + 255) / 256), 256, 0, stream>>>(W2, W2h, W2l, w2n4);

  // ---- CSR build ----
  (void)hipMemsetAsync(cnt, 0, (size_t)N * 4, stream);
  (void)hipMemsetAsync(cursor, 0, (size_t)N * 4, stream);
  int eb = (Etot + 255) / 256;
  hist_kernel<<<eb, 256, 0, stream>>>(ei, E, N, cnt);
  scan_kernel<<<1, 1024, 0, stream>>>(cnt, row_start, N);
  scatter_kernel<<<eb, 256, 0, stream>>>(ei, E, N, row_start, cursor, csr_src);

  int mb = (N + 63) / 64;          // 313
  int mb8 = (mb + 7) / 8;          // 40
  int gemm_grid4 = 8 * 4 * mb8;    // NB=4 (HID=256)
  int gemm_grid2 = 8 * 2 * mb8;    // NB=2 (OUTC=128)

  // ---- layer 0: 512 -> 8x32, relu (A = x f32, in-kernel split) ----
  gemm_mfma<true><<<gemm_grid4, 256, 0, stream>>>(x, nullptr, nullptr, W0h, W0l,
                                                  Hb, Hb16, N, HID, FIN, 4);
  alpha_kernel<8, 32><<<N, 64, 0, stream>>>(Hb, asr0, adt0, as_, ad_, N);
  agg_kernel<8, 32, true><<<N, 64, 0, stream>>>(Hb16, as_, ad_, row_start, csr_src, b0,
                                                nullptr, act_h, act_l, N);

  // ---- layer 1: 256 -> 8x32, relu (A = act split; h_pen -> d_out f32 + split) ----
  gemm_mfma<false><<<gemm_grid4, 256, 0, stream>>>(nullptr, act_h, act_l, W1h, W1l,
                                                   Hb, Hb16, N, HID, HID, 4);
  alpha_kernel<8, 32><<<N, 64, 0, stream>>>(Hb, asr1, adt1, as_, ad_, N);
  agg_kernel<8, 32, true><<<N, 64, 0, stream>>>(Hb16, as_, ad_, row_start, csr_src, b1,
                                                hpen, h_h, h_l, N);

  // ---- layer 2: 256 -> 128, 1 head, no relu (A = h_pen split) ----
  gemm_mfma<false><<<gemm_grid2, 256, 0, stream>>>(nullptr, h_h, h_l, W2h, W2l,
                                                   Hb, Hb16, N, OUTC, HID, 2);
  alpha_kernel<1, 128><<<N, 64, 0, stream>>>(Hb, asr2, adt2, as_, ad_, N);
  agg_kernel<1, 128, false><<<N, 64, 0, stream>>>(Hb16, as_, ad_, row_start, csr_src, b2,
                                                  out2, nullptr, nullptr, N);
}

// Round 17
// 248.108 us; speedup vs baseline: 1.0347x; 1.0347x over previous
//
#include <hip/hip_runtime.h>
#include <hip/hip_bf16.h>

// d_out is FLOAT32. h_pen = first N*256 f32, h = next N*128 f32.

using bf16 = __hip_bfloat16;

typedef __attribute__((ext_vector_type(8))) short bf16x8;
typedef __attribute__((ext_vector_type(4))) short short4v;
typedef __attribute__((ext_vector_type(4))) float f32x4;
typedef __attribute__((ext_vector_type(2))) float f32x2;
typedef __attribute__((ext_vector_type(2))) unsigned int uint2v;

__device__ __forceinline__ float u2f(unsigned u) { union { float f; unsigned u; } c; c.u = u; return c.f; }
__device__ __forceinline__ unsigned f2u(float x) { union { float f; unsigned u; } c; c.f = x; return c.u; }
__device__ __forceinline__ short bfbits(float x) {
  unsigned xu = f2u(x);
  return (short)((xu + 0x7FFF + ((xu >> 16) & 1)) >> 16);
}

// ============================ CSR build (dst-sorted) ============================
__global__ void hist_kernel(const int* __restrict__ ei, int E, int N, int* __restrict__ cnt) {
  int e = blockIdx.x * 256 + threadIdx.x;
  if (e >= E + N) return;
  int dst = (e < E) ? ei[E + e] : (e - E);
  atomicAdd(&cnt[dst], 1);
}

__global__ __launch_bounds__(1024) void scan_kernel(const int* __restrict__ cnt,
                                                    int* __restrict__ row_start, int N) {
  __shared__ int part[1024];
  int t = threadIdx.x;
  int chunk = (N + 1023) / 1024;
  int lo = t * chunk; if (lo > N) lo = N;
  int hi = lo + chunk; if (hi > N) hi = N;
  int s = 0;
  for (int i = lo; i < hi; ++i) s += cnt[i];
  part[t] = s;
  __syncthreads();
  for (int off = 1; off < 1024; off <<= 1) {
    int add = (t >= off) ? part[t - off] : 0;
    __syncthreads();
    part[t] += add;
    __syncthreads();
  }
  int run = part[t] - s;
  for (int i = lo; i < hi; ++i) { row_start[i] = run; run += cnt[i]; }
  if (t == 1023) row_start[N] = part[1023];
}

__global__ void scatter_kernel(const int* __restrict__ ei, int E, int N,
                               const int* __restrict__ row_start, int* __restrict__ cursor,
                               int* __restrict__ csr_src) {
  int e = blockIdx.x * 256 + threadIdx.x;
  if (e >= E + N) return;
  int src, dst;
  if (e < E) { src = ei[e]; dst = ei[E + e]; }
  else       { src = e - E; dst = e - E; }
  int pos = atomicAdd(&cursor[dst], 1);
  csr_src[row_start[dst] + pos] = src;
}

// ============================ f32 -> bf16 hi/lo presplit (weights only) ============================
__global__ void split_kernel(const float* __restrict__ in, unsigned short* __restrict__ hi,
                             unsigned short* __restrict__ lo, long long n4) {
  long long i = (long long)blockIdx.x * 256 + threadIdx.x;
  if (i >= n4) return;
  f32x4 v = *(const f32x4*)(in + i * 4);
  short4v h, l;
#pragma unroll
  for (int k = 0; k < 4; ++k) {
    short hb = bfbits(v[k]);
    h[k] = hb;
    l[k] = bfbits(v[k] - u2f(((unsigned)(unsigned short)hb) << 16));
  }
  *(short4v*)(hi + i * 4) = h;
  *(short4v*)(lo + i * 4) = l;
}

// ============================ MFMA GEMM: C = A * B^T (+ bf16 mirror) ============================
// Tile 128x64, BK=32, 4 waves (2M x 2N), wave computes 64x32 (4x2 fragments).
// A: f32, split in-kernel. B: presplit hi/lo bf16 (pure copy staging).
#define LDPA 40  // LDS pitch in shorts (80B: 16B-aligned, breaks pow2 stride)

__device__ __forceinline__ bf16x8 make_frag(const short* S, int row, int g) {
  short4v klo = *(const short4v*)&S[row * LDPA + g * 4];
  short4v khi = *(const short4v*)&S[row * LDPA + 16 + g * 4];
  bf16x8 r;
#pragma unroll
  for (int i = 0; i < 4; ++i) { r[i] = klo[i]; r[i + 4] = khi[i]; }
  return r;
}

__global__ __launch_bounds__(256) void gemm_mfma(const float* __restrict__ Af,
                                                 const unsigned short* __restrict__ Bhg,
                                                 const unsigned short* __restrict__ Blg,
                                                 float* __restrict__ C,
                                                 unsigned short* __restrict__ C16,
                                                 int M, int Nn, int K, int NB) {
  // XCD-aware: same-bm blocks differ by 8 in id -> same XCD -> A panel L2 reuse.
  int id = blockIdx.x;
  int r8 = id & 7;
  int q  = id >> 3;
  int bn = q % NB;
  int bm = r8 + 8 * (q / NB);
  if (bm * 128 >= M) return;

  __shared__ short Ah[128 * LDPA];
  __shared__ short Al[128 * LDPA];
  __shared__ short Bh[64 * LDPA];
  __shared__ short Bl[64 * LDPA];
  int t = threadIdx.x;
  int w = t >> 6, l = t & 63;
  int g = l >> 4, lr = l & 15;
  int wm = w >> 1, wn = w & 1;

  f32x4 acc[4][2];
#pragma unroll
  for (int a = 0; a < 4; ++a)
#pragma unroll
    for (int j = 0; j < 2; ++j) acc[a][j] = (f32x4)(0.f);

  int srow = t >> 2;            // 0..63
  int sseg = (t & 3) * 8;       // 0,8,16,24

  for (int kt = 0; kt < K; kt += 32) {
    __syncthreads();
    // ---- stage B (64 rows): pure 16B copies from presplit ----
    {
      size_t boff = (size_t)(bn * 64 + srow) * K + kt + sseg;
      int4 vh = *(const int4*)(Bhg + boff);
      int4 vl = *(const int4*)(Blg + boff);
      *(int4*)&Bh[srow * LDPA + sseg] = vh;
      *(int4*)&Bl[srow * LDPA + sseg] = vl;
    }
    // ---- stage A (128 rows, two passes), split f32 -> hi/lo ----
#pragma unroll
    for (int p = 0; p < 2; ++p) {
      int arow = p * 64 + srow;
      int gm = bm * 128 + arow;
      f32x4 v0 = (f32x4)(0.f), v1 = (f32x4)(0.f);
      if (gm < M) {
        const float* Arow = Af + (size_t)gm * K + kt + sseg;
        v0 = *(const f32x4*)Arow;
        v1 = *(const f32x4*)(Arow + 4);
      }
      short4v h0, l0, h1, l1;
#pragma unroll
      for (int i = 0; i < 4; ++i) {
        short hb0 = bfbits(v0[i]);
        l0[i] = bfbits(v0[i] - u2f(((unsigned)(unsigned short)hb0) << 16));
        h0[i] = hb0;
        short hb1 = bfbits(v1[i]);
        l1[i] = bfbits(v1[i] - u2f(((unsigned)(unsigned short)hb1) << 16));
        h1[i] = hb1;
      }
      *(short4v*)&Ah[arow * LDPA + sseg]     = h0;
      *(short4v*)&Ah[arow * LDPA + sseg + 4] = h1;
      *(short4v*)&Al[arow * LDPA + sseg]     = l0;
      *(short4v*)&Al[arow * LDPA + sseg + 4] = l1;
    }
    __syncthreads();

    // ---- fragments (registers) + MFMA ----
    bf16x8 ahf[4], alf[4], bhf[2], blf[2];
#pragma unroll
    for (int a = 0; a < 4; ++a) {
      int arow = wm * 64 + a * 16 + lr;
      ahf[a] = make_frag(Ah, arow, g);
      alf[a] = make_frag(Al, arow, g);
    }
#pragma unroll
    for (int j = 0; j < 2; ++j) {
      int brow = wn * 32 + j * 16 + lr;
      bhf[j] = make_frag(Bh, brow, g);
      blf[j] = make_frag(Bl, brow, g);
    }
#pragma unroll
    for (int a = 0; a < 4; ++a)
#pragma unroll
      for (int j = 0; j < 2; ++j) {
        acc[a][j] = __builtin_amdgcn_mfma_f32_16x16x32_bf16(ahf[a], bhf[j], acc[a][j], 0, 0, 0);
        acc[a][j] = __builtin_amdgcn_mfma_f32_16x16x32_bf16(alf[a], bhf[j], acc[a][j], 0, 0, 0);
        acc[a][j] = __builtin_amdgcn_mfma_f32_16x16x32_bf16(ahf[a], blf[j], acc[a][j], 0, 0, 0);
      }
  }

  // C/D layout (HW-verified m89): col = lane&15, row = (lane>>4)*4 + reg
#pragma unroll
  for (int a = 0; a < 4; ++a)
#pragma unroll
    for (int j = 0; j < 2; ++j)
#pragma unroll
      for (int r = 0; r < 4; ++r) {
        int row = bm * 128 + wm * 64 + a * 16 + g * 4 + r;
        int col = bn * 64 + wn * 32 + j * 16 + lr;
        if (row < M) {
          float v = acc[a][j][r];
          C[(size_t)row * Nn + col] = v;
          C16[(size_t)row * Nn + col] = (unsigned short)bfbits(v);
        }
      }
}

// ============================ alpha projections: one wave per node ============================
template <int H, int C>
__global__ __launch_bounds__(64) void alpha_kernel(const float* __restrict__ Hb,
                                                   const float* __restrict__ a_src,
                                                   const float* __restrict__ a_dst,
                                                   float* __restrict__ as_,
                                                   float* __restrict__ ad_, int N) {
  constexpr int HC = H * C;
  constexpr int EPL = HC / 64;
  constexpr int LPH = 64 / H;
  int n = blockIdx.x;
  int l = threadIdx.x;
  const float* row = Hb + (size_t)n * HC + l * EPL;
  float s1 = 0.f, s2 = 0.f;
  if constexpr (EPL == 4) {
    f32x4 v = *(const f32x4*)row;
    f32x4 a1 = *(const f32x4*)(a_src + l * 4);
    f32x4 a2 = *(const f32x4*)(a_dst + l * 4);
#pragma unroll
    for (int k = 0; k < 4; ++k) { s1 += v[k] * a1[k]; s2 += v[k] * a2[k]; }
  } else {
    f32x2 v = *(const f32x2*)row;
    f32x2 a1 = *(const f32x2*)(a_src + l * 2);
    f32x2 a2 = *(const f32x2*)(a_dst + l * 2);
#pragma unroll
    for (int k = 0; k < 2; ++k) { s1 += v[k] * a1[k]; s2 += v[k] * a2[k]; }
  }
#pragma unroll
  for (int mask = 1; mask < LPH; mask <<= 1) {
    s1 += __shfl_xor(s1, mask);
    s2 += __shfl_xor(s2, mask);
  }
  if ((l & (LPH - 1)) == 0) {
    int h = l / LPH;
    as_[n * H + h] = s1;
    ad_[n * H + h] = s2;
  }
}

// ============================ softmax + aggregate (bf16 gather, 2-way unroll) ============================
template <int H, int C, bool RELU>
__global__ __launch_bounds__(64) void agg_kernel(const unsigned short* __restrict__ Hb16,
                                                 const float* __restrict__ as_,
                                                 const float* __restrict__ ad_,
                                                 const int* __restrict__ row_start,
                                                 const int* __restrict__ csr_src,
                                                 const float* __restrict__ bias,
                                                 float* __restrict__ out, int N) {
  int n = blockIdx.x;
  if (n >= N) return;
  int l = threadIdx.x;
  int s = row_start[n], e = row_start[n + 1];

  constexpr int LPH = 64 / H;
  constexpr int CPL = C / LPH;
  constexpr int HC = H * C;
  int h2 = l / LPH;
  int cb = (l % LPH) * CPL;
  float ad2 = ad_[n * H + h2];

  float acc[CPL];
#pragma unroll
  for (int c = 0; c < CPL; ++c) acc[c] = 0.f;
  float denom = 0.f;

  int j = s;
  for (; j + 1 < e; j += 2) {
    int s0 = csr_src[j], s1v = csr_src[j + 1];
    float x0 = as_[s0 * H + h2] + ad2;
    float x1 = as_[s1v * H + h2] + ad2;
    x0 = x0 > 0.f ? x0 : 0.2f * x0;
    x1 = x1 > 0.f ? x1 : 0.2f * x1;
    float p0 = __expf(x0), p1 = __expf(x1);
    denom += p0 + p1;
    const unsigned short* hp0 = Hb16 + (size_t)s0 * HC + h2 * C + cb;
    const unsigned short* hp1 = Hb16 + (size_t)s1v * HC + h2 * C + cb;
    if constexpr (CPL == 4) {
      uint2v u0 = *(const uint2v*)hp0;
      uint2v u1 = *(const uint2v*)hp1;
#pragma unroll
      for (int c = 0; c < 2; ++c) {
        acc[2 * c]     += p0 * u2f(u0[c] << 16)         + p1 * u2f(u1[c] << 16);
        acc[2 * c + 1] += p0 * u2f(u0[c] & 0xFFFF0000u) + p1 * u2f(u1[c] & 0xFFFF0000u);
      }
    } else {
      unsigned u0 = *(const unsigned*)hp0;
      unsigned u1 = *(const unsigned*)hp1;
      acc[0] += p0 * u2f(u0 << 16)         + p1 * u2f(u1 << 16);
      acc[1] += p0 * u2f(u0 & 0xFFFF0000u) + p1 * u2f(u1 & 0xFFFF0000u);
    }
  }
  if (j < e) {
    int s0 = csr_src[j];
    float x0 = as_[s0 * H + h2] + ad2;
    x0 = x0 > 0.f ? x0 : 0.2f * x0;
    float p0 = __expf(x0);
    denom += p0;
    const unsigned short* hp0 = Hb16 + (size_t)s0 * HC + h2 * C + cb;
    if constexpr (CPL == 4) {
      uint2v u0 = *(const uint2v*)hp0;
#pragma unroll
      for (int c = 0; c < 2; ++c) {
        acc[2 * c]     += p0 * u2f(u0[c] << 16);
        acc[2 * c + 1] += p0 * u2f(u0[c] & 0xFFFF0000u);
      }
    } else {
      unsigned u0 = *(const unsigned*)hp0;
      acc[0] += p0 * u2f(u0 << 16);
      acc[1] += p0 * u2f(u0 & 0xFFFF0000u);
    }
  }

  float inv = 1.f / (denom + 1e-16f);
#pragma unroll
  for (int c = 0; c < CPL; ++c) {
    float v = acc[c] * inv + bias[h2 * C + cb + c];
    if (RELU) v = fmaxf(v, 0.f);
    out[(size_t)n * HC + h2 * C + cb + c] = v;
  }
}

// ============================ launch ============================
extern "C" void kernel_launch(void* const* d_in, const int* in_sizes, int n_in,
                              void* d_out, int out_size, void* d_ws, size_t ws_size,
                              hipStream_t stream) {
  const float* x    = (const float*)d_in[0];
  const int*   ei   = (const int*)d_in[1];
  const float* W0   = (const float*)d_in[2];
  const float* asr0 = (const float*)d_in[3];
  const float* adt0 = (const float*)d_in[4];
  const float* b0   = (const float*)d_in[5];
  const float* W1   = (const float*)d_in[6];
  const float* asr1 = (const float*)d_in[7];
  const float* adt1 = (const float*)d_in[8];
  const float* b1   = (const float*)d_in[9];
  const float* W2   = (const float*)d_in[10];
  const float* asr2 = (const float*)d_in[11];
  const float* adt2 = (const float*)d_in[12];
  const float* b2   = (const float*)d_in[13];

  const int FIN = 512, HID = 256, OUTC = 128;
  int N = in_sizes[0] / FIN;          // 20000
  int E = in_sizes[1] / 2;            // 320000
  int Etot = E + N;

  char* ws = (char*)d_ws;
  size_t off = 0;
  auto alloc = [&](size_t bytes) -> void* {
    void* p = ws + off;
    off = (off + bytes + 255) & ~(size_t)255;
    return p;
  };
  int* cnt       = (int*)alloc((size_t)N * 4);
  int* cursor    = (int*)alloc((size_t)N * 4);
  int* row_start = (int*)alloc((size_t)(N + 1) * 4);
  int* csr_src   = (int*)alloc((size_t)Etot * 4);
  float* as_     = (float*)alloc((size_t)N * 8 * 4);
  float* ad_     = (float*)alloc((size_t)N * 8 * 4);
  float* Hb      = (float*)alloc((size_t)N * HID * 4);                  // GEMM out f32
  unsigned short* Hb16 = (unsigned short*)alloc((size_t)N * HID * 2);   // GEMM out bf16 mirror
  float* act     = (float*)alloc((size_t)N * HID * 4);                  // layer activation f32
  unsigned short* W0h = (unsigned short*)alloc((size_t)HID * FIN * 2);
  unsigned short* W0l = (unsigned short*)alloc((size_t)HID * FIN * 2);
  unsigned short* W1h = (unsigned short*)alloc((size_t)HID * HID * 2);
  unsigned short* W1l = (unsigned short*)alloc((size_t)HID * HID * 2);
  unsigned short* W2h = (unsigned short*)alloc((size_t)OUTC * HID * 2);
  unsigned short* W2l = (unsigned short*)alloc((size_t)OUTC * HID * 2);

  float* hpen = (float*)d_out;                       // [N, 256] f32
  float* out2 = (float*)d_out + (size_t)N * HID;     // [N, 128] f32

  // ---- presplit weights (once) ----
  long long w0n4 = (long long)HID * FIN / 4, w1n4 = (long long)HID * HID / 4,
            w2n4 = (long long)OUTC * HID / 4;
  split_kernel<<<(int)((w0n4 + 255) / 256), 256, 0, stream>>>(W0, W0h, W0l, w0n4);
  split_kernel<<<(int)((w1n4 + 255) / 256), 256, 0, stream>>>(W1, W1h, W1l, w1n4);
  split_kernel<<<(int)((w2n4 + 255) / 256), 256, 0, stream>>>(W2, W2h, W2l, w2n4);

  // ---- CSR build ----
  (void)hipMemsetAsync(cnt, 0, (size_t)N * 4, stream);
  (void)hipMemsetAsync(cursor, 0, (size_t)N * 4, stream);
  int eb = (Etot + 255) / 256;
  hist_kernel<<<eb, 256, 0, stream>>>(ei, E, N, cnt);
  scan_kernel<<<1, 1024, 0, stream>>>(cnt, row_start, N);
  scatter_kernel<<<eb, 256, 0, stream>>>(ei, E, N, row_start, cursor, csr_src);

  int mb = (N + 127) / 128;        // 157
  int mb8 = (mb + 7) / 8;          // 20
  int grid4 = 8 * 4 * mb8;         // NB=4 (HID=256)
  int grid2 = 8 * 2 * mb8;         // NB=2 (OUTC=128)

  // ---- layer 0: 512 -> 8x32, relu ----
  gemm_mfma<<<grid4, 256, 0, stream>>>(x, W0h, W0l, Hb, Hb16, N, HID, FIN, 4);
  alpha_kernel<8, 32><<<N, 64, 0, stream>>>(Hb, asr0, adt0, as_, ad_, N);
  agg_kernel<8, 32, true><<<N, 64, 0, stream>>>(Hb16, as_, ad_, row_start, csr_src, b0,
                                                act, N);

  // ---- layer 1: 256 -> 8x32, relu (h_pen -> d_out f32) ----
  gemm_mfma<<<grid4, 256, 0, stream>>>(act, W1h, W1l, Hb, Hb16, N, HID, HID, 4);
  alpha_kernel<8, 32><<<N, 64, 0, stream>>>(Hb, asr1, adt1, as_, ad_, N);
  agg_kernel<8, 32, true><<<N, 64, 0, stream>>>(Hb16, as_, ad_, row_start, csr_src, b1,
                                                hpen, N);

  // ---- layer 2: 256 -> 128, 1 head, no relu (reads h_pen from d_out) ----
  gemm_mfma<<<grid2, 256, 0, stream>>>(hpen, W2h, W2l, Hb, Hb16, N, OUTC, HID, 2);
  alpha_kernel<1, 128><<<N, 64, 0, stream>>>(Hb, asr2, adt2, as_, ad_, N);
  agg_kernel<1, 128, false><<<N, 64, 0, stream>>>(Hb16, as_, ad_, row_start, csr_src, b2,
                                                  out2, N);
}

// Round 18
// 232.910 us; speedup vs baseline: 1.1022x; 1.0653x over previous
//
#include <hip/hip_runtime.h>
#include <hip/hip_bf16.h>

// d_out is FLOAT32. h_pen = first N*256 f32, h = next N*128 f32.

using bf16 = __hip_bfloat16;

typedef __attribute__((ext_vector_type(8))) short bf16x8;
typedef __attribute__((ext_vector_type(4))) short short4v;
typedef __attribute__((ext_vector_type(4))) float f32x4;
typedef __attribute__((ext_vector_type(2))) float f32x2;
typedef __attribute__((ext_vector_type(2))) unsigned int uint2v;

__device__ __forceinline__ float u2f(unsigned u) { union { float f; unsigned u; } c; c.u = u; return c.f; }
__device__ __forceinline__ unsigned f2u(float x) { union { float f; unsigned u; } c; c.f = x; return c.u; }
__device__ __forceinline__ short bfbits(float x) {
  unsigned xu = f2u(x);
  return (short)((xu + 0x7FFF + ((xu >> 16) & 1)) >> 16);
}

// ============================ CSR build (dst-sorted) ============================
__global__ void hist_kernel(const int* __restrict__ ei, int E, int N, int* __restrict__ cnt) {
  int e = blockIdx.x * 256 + threadIdx.x;
  if (e >= E + N) return;
  int dst = (e < E) ? ei[E + e] : (e - E);
  atomicAdd(&cnt[dst], 1);
}

__global__ __launch_bounds__(1024) void scan_kernel(const int* __restrict__ cnt,
                                                    int* __restrict__ row_start, int N) {
  __shared__ int part[1024];
  int t = threadIdx.x;
  int chunk = (N + 1023) / 1024;
  int lo = t * chunk; if (lo > N) lo = N;
  int hi = lo + chunk; if (hi > N) hi = N;
  int s = 0;
  for (int i = lo; i < hi; ++i) s += cnt[i];
  part[t] = s;
  __syncthreads();
  for (int off = 1; off < 1024; off <<= 1) {
    int add = (t >= off) ? part[t - off] : 0;
    __syncthreads();
    part[t] += add;
    __syncthreads();
  }
  int run = part[t] - s;
  for (int i = lo; i < hi; ++i) { row_start[i] = run; run += cnt[i]; }
  if (t == 1023) row_start[N] = part[1023];
}

__global__ void scatter_kernel(const int* __restrict__ ei, int E, int N,
                               const int* __restrict__ row_start, int* __restrict__ cursor,
                               int* __restrict__ csr_src) {
  int e = blockIdx.x * 256 + threadIdx.x;
  if (e >= E + N) return;
  int src, dst;
  if (e < E) { src = ei[e]; dst = ei[E + e]; }
  else       { src = e - E; dst = e - E; }
  int pos = atomicAdd(&cursor[dst], 1);
  csr_src[row_start[dst] + pos] = src;
}

// ============================ fused weight presplit (all 3 weights, one launch) ============================
__global__ void split3_kernel(const float* __restrict__ W0, const float* __restrict__ W1,
                              const float* __restrict__ W2,
                              unsigned short* __restrict__ W0h, unsigned short* __restrict__ W0l,
                              unsigned short* __restrict__ W1h, unsigned short* __restrict__ W1l,
                              unsigned short* __restrict__ W2h, unsigned short* __restrict__ W2l,
                              int n0_4, int n1_4, int n2_4) {
  int i = blockIdx.x * 256 + threadIdx.x;
  const float* in; unsigned short *hi, *lo; int idx;
  if (i < n0_4)                { in = W0; hi = W0h; lo = W0l; idx = i; }
  else if (i < n0_4 + n1_4)    { in = W1; hi = W1h; lo = W1l; idx = i - n0_4; }
  else if (i < n0_4 + n1_4 + n2_4) { in = W2; hi = W2h; lo = W2l; idx = i - n0_4 - n1_4; }
  else return;
  f32x4 v = *(const f32x4*)(in + (size_t)idx * 4);
  short4v h, l;
#pragma unroll
  for (int k = 0; k < 4; ++k) {
    short hb = bfbits(v[k]);
    h[k] = hb;
    l[k] = bfbits(v[k] - u2f(((unsigned)(unsigned short)hb) << 16));
  }
  *(short4v*)(hi + (size_t)idx * 4) = h;
  *(short4v*)(lo + (size_t)idx * 4) = l;
}

// ============================ MFMA GEMM 64x64 + optional fused alpha epilogue ============================
// A: f32, split in-kernel. B: presplit hi/lo bf16 (pure copy staging).
// FUSE8: H=8/C=32 alpha fused (block's 64 cols = heads 2bn, 2bn+1); no f32 C write.
// WF32: write f32 C (layer 2, feeds standalone alpha).
#define LDP 40  // LDS pitch in shorts (80B: 16B-aligned, breaks pow2 stride)

__device__ __forceinline__ bf16x8 make_frag(const short* S, int row, int g) {
  short4v klo = *(const short4v*)&S[row * LDP + g * 4];
  short4v khi = *(const short4v*)&S[row * LDP + 16 + g * 4];
  bf16x8 r;
#pragma unroll
  for (int i = 0; i < 4; ++i) { r[i] = klo[i]; r[i + 4] = khi[i]; }
  return r;
}

template <bool FUSE8, bool WF32>
__global__ __launch_bounds__(256) void gemm_mfma(const float* __restrict__ Af,
                                                 const unsigned short* __restrict__ Bhg,
                                                 const unsigned short* __restrict__ Blg,
                                                 const float* __restrict__ Asrc,
                                                 const float* __restrict__ Adst,
                                                 float* __restrict__ as_,
                                                 float* __restrict__ ad_,
                                                 float* __restrict__ C,
                                                 unsigned short* __restrict__ C16,
                                                 int M, int Nn, int K, int NB) {
  // XCD-aware: same-bm blocks differ by 8 in id -> same XCD -> A panel L2 reuse.
  int id = blockIdx.x;
  int r8 = id & 7;
  int q  = id >> 3;
  int bn = q % NB;
  int bm = r8 + 8 * (q / NB);
  if (bm * 64 >= M) return;

  __shared__ short Ah[64 * LDP];
  __shared__ short Al[64 * LDP];
  __shared__ short Bh[64 * LDP];
  __shared__ short Bl[64 * LDP];
  int t = threadIdx.x;
  int w = t >> 6, l = t & 63;
  int g = l >> 4, lr = l & 15;

  f32x4 acc[4];
#pragma unroll
  for (int j = 0; j < 4; ++j) acc[j] = (f32x4)(0.f);

  int srow = t >> 2;            // 0..63
  int sseg = (t & 3) * 8;       // 0,8,16,24
  int gm = bm * 64 + srow;
  int gn = bn * 64 + srow;

  for (int kt = 0; kt < K; kt += 32) {
    __syncthreads();
    // ---- stage B: pure 16B copies from presplit ----
    {
      size_t boff = (size_t)gn * K + kt + sseg;
      int4 vh = *(const int4*)(Bhg + boff);
      int4 vl = *(const int4*)(Blg + boff);
      *(int4*)&Bh[srow * LDP + sseg] = vh;
      *(int4*)&Bl[srow * LDP + sseg] = vl;
    }
    // ---- stage A: split f32 -> hi/lo ----
    {
      f32x4 v0 = (f32x4)(0.f), v1 = (f32x4)(0.f);
      if (gm < M) {
        const float* Arow = Af + (size_t)gm * K + kt + sseg;
        v0 = *(const f32x4*)Arow;
        v1 = *(const f32x4*)(Arow + 4);
      }
      short4v h0, l0, h1, l1;
#pragma unroll
      for (int i = 0; i < 4; ++i) {
        short hb0 = bfbits(v0[i]);
        l0[i] = bfbits(v0[i] - u2f(((unsigned)(unsigned short)hb0) << 16));
        h0[i] = hb0;
        short hb1 = bfbits(v1[i]);
        l1[i] = bfbits(v1[i] - u2f(((unsigned)(unsigned short)hb1) << 16));
        h1[i] = hb1;
      }
      *(short4v*)&Ah[srow * LDP + sseg]     = h0;
      *(short4v*)&Ah[srow * LDP + sseg + 4] = h1;
      *(short4v*)&Al[srow * LDP + sseg]     = l0;
      *(short4v*)&Al[srow * LDP + sseg + 4] = l1;
    }
    __syncthreads();

    int arow = w * 16 + lr;
    bf16x8 ah = make_frag(Ah, arow, g);
    bf16x8 al = make_frag(Al, arow, g);
#pragma unroll
    for (int j = 0; j < 4; ++j) {
      int brow = j * 16 + lr;
      bf16x8 bh = make_frag(Bh, brow, g);
      bf16x8 bl = make_frag(Bl, brow, g);
      acc[j] = __builtin_amdgcn_mfma_f32_16x16x32_bf16(ah, bh, acc[j], 0, 0, 0);
      acc[j] = __builtin_amdgcn_mfma_f32_16x16x32_bf16(al, bh, acc[j], 0, 0, 0);
      acc[j] = __builtin_amdgcn_mfma_f32_16x16x32_bf16(ah, bl, acc[j], 0, 0, 0);
    }
  }

  // ---- C write. C/D layout (HW-verified m89): col = lane&15, row = (lane>>4)*4 + reg ----
#pragma unroll
  for (int j = 0; j < 4; ++j) {
#pragma unroll
    for (int r = 0; r < 4; ++r) {
      int row = bm * 64 + w * 16 + g * 4 + r;
      int col = bn * 64 + j * 16 + lr;
      if (row < M) {
        float v = acc[j][r];
        if constexpr (WF32) C[(size_t)row * Nn + col] = v;
        C16[(size_t)row * Nn + col] = (unsigned short)bfbits(v);
      }
    }
  }

  // ---- fused alpha epilogue (H=8, C=32): block covers heads 2bn, 2bn+1 ----
  if constexpr (FUSE8) {
    float cs[4], cd[4];
#pragma unroll
    for (int j = 0; j < 4; ++j) {
      cs[j] = Asrc[bn * 64 + j * 16 + lr];
      cd[j] = Adst[bn * 64 + j * 16 + lr];
    }
#pragma unroll
    for (int r = 0; r < 4; ++r) {
      float sA0 = acc[0][r] * cs[0] + acc[1][r] * cs[1];   // head 2bn
      float sA1 = acc[2][r] * cs[2] + acc[3][r] * cs[3];   // head 2bn+1
      float sD0 = acc[0][r] * cd[0] + acc[1][r] * cd[1];
      float sD1 = acc[2][r] * cd[2] + acc[3][r] * cd[3];
#pragma unroll
      for (int mask = 1; mask < 16; mask <<= 1) {
        sA0 += __shfl_xor(sA0, mask);
        sA1 += __shfl_xor(sA1, mask);
        sD0 += __shfl_xor(sD0, mask);
        sD1 += __shfl_xor(sD1, mask);
      }
      if (lr == 0) {
        int row = bm * 64 + w * 16 + g * 4 + r;
        if (row < M) {
          as_[row * 8 + bn * 2]     = sA0;
          as_[row * 8 + bn * 2 + 1] = sA1;
          ad_[row * 8 + bn * 2]     = sD0;
          ad_[row * 8 + bn * 2 + 1] = sD1;
        }
      }
    }
  }
}

// ============================ alpha projection (layer 2 only: H=1, C=128) ============================
template <int H, int C>
__global__ __launch_bounds__(64) void alpha_kernel(const float* __restrict__ Hb,
                                                   const float* __restrict__ a_src,
                                                   const float* __restrict__ a_dst,
                                                   float* __restrict__ as_,
                                                   float* __restrict__ ad_, int N) {
  constexpr int HC = H * C;
  constexpr int EPL = HC / 64;
  constexpr int LPH = 64 / H;
  int n = blockIdx.x;
  int l = threadIdx.x;
  const float* row = Hb + (size_t)n * HC + l * EPL;
  float s1 = 0.f, s2 = 0.f;
  if constexpr (EPL == 4) {
    f32x4 v = *(const f32x4*)row;
    f32x4 a1 = *(const f32x4*)(a_src + l * 4);
    f32x4 a2 = *(const f32x4*)(a_dst + l * 4);
#pragma unroll
    for (int k = 0; k < 4; ++k) { s1 += v[k] * a1[k]; s2 += v[k] * a2[k]; }
  } else {
    f32x2 v = *(const f32x2*)row;
    f32x2 a1 = *(const f32x2*)(a_src + l * 2);
    f32x2 a2 = *(const f32x2*)(a_dst + l * 2);
#pragma unroll
    for (int k = 0; k < 2; ++k) { s1 += v[k] * a1[k]; s2 += v[k] * a2[k]; }
  }
#pragma unroll
  for (int mask = 1; mask < LPH; mask <<= 1) {
    s1 += __shfl_xor(s1, mask);
    s2 += __shfl_xor(s2, mask);
  }
  if ((l & (LPH - 1)) == 0) {
    int h = l / LPH;
    as_[n * H + h] = s1;
    ad_[n * H + h] = s2;
  }
}

// ============================ softmax + aggregate (bf16 gather, 2-way unroll) ============================
template <int H, int C, bool RELU>
__global__ __launch_bounds__(64) void agg_kernel(const unsigned short* __restrict__ Hb16,
                                                 const float* __restrict__ as_,
                                                 const float* __restrict__ ad_,
                                                 const int* __restrict__ row_start,
                                                 const int* __restrict__ csr_src,
                                                 const float* __restrict__ bias,
                                                 float* __restrict__ out, int N) {
  int n = blockIdx.x;
  if (n >= N) return;
  int l = threadIdx.x;
  int s = row_start[n], e = row_start[n + 1];

  constexpr int LPH = 64 / H;
  constexpr int CPL = C / LPH;
  constexpr int HC = H * C;
  int h2 = l / LPH;
  int cb = (l % LPH) * CPL;
  float ad2 = ad_[n * H + h2];

  float acc[CPL];
#pragma unroll
  for (int c = 0; c < CPL; ++c) acc[c] = 0.f;
  float denom = 0.f;

  int j = s;
  for (; j + 1 < e; j += 2) {
    int s0 = csr_src[j], s1v = csr_src[j + 1];
    float x0 = as_[s0 * H + h2] + ad2;
    float x1 = as_[s1v * H + h2] + ad2;
    x0 = x0 > 0.f ? x0 : 0.2f * x0;
    x1 = x1 > 0.f ? x1 : 0.2f * x1;
    float p0 = __expf(x0), p1 = __expf(x1);
    denom += p0 + p1;
    const unsigned short* hp0 = Hb16 + (size_t)s0 * HC + h2 * C + cb;
    const unsigned short* hp1 = Hb16 + (size_t)s1v * HC + h2 * C + cb;
    if constexpr (CPL == 4) {
      uint2v u0 = *(const uint2v*)hp0;
      uint2v u1 = *(const uint2v*)hp1;
#pragma unroll
      for (int c = 0; c < 2; ++c) {
        acc[2 * c]     += p0 * u2f(u0[c] << 16)         + p1 * u2f(u1[c] << 16);
        acc[2 * c + 1] += p0 * u2f(u0[c] & 0xFFFF0000u) + p1 * u2f(u1[c] & 0xFFFF0000u);
      }
    } else {
      unsigned u0 = *(const unsigned*)hp0;
      unsigned u1 = *(const unsigned*)hp1;
      acc[0] += p0 * u2f(u0 << 16)         + p1 * u2f(u1 << 16);
      acc[1] += p0 * u2f(u0 & 0xFFFF0000u) + p1 * u2f(u1 & 0xFFFF0000u);
    }
  }
  if (j < e) {
    int s0 = csr_src[j];
    float x0 = as_[s0 * H + h2] + ad2;
    x0 = x0 > 0.f ? x0 : 0.2f * x0;
    float p0 = __expf(x0);
    denom += p0;
    const unsigned short* hp0 = Hb16 + (size_t)s0 * HC + h2 * C + cb;
    if constexpr (CPL == 4) {
      uint2v u0 = *(const uint2v*)hp0;
#pragma unroll
      for (int c = 0; c < 2; ++c) {
        acc[2 * c]     += p0 * u2f(u0[c] << 16);
        acc[2 * c + 1] += p0 * u2f(u0[c] & 0xFFFF0000u);
      }
    } else {
      unsigned u0 = *(const unsigned*)hp0;
      acc[0] += p0 * u2f(u0 << 16);
      acc[1] += p0 * u2f(u0 & 0xFFFF0000u);
    }
  }

  float inv = 1.f / (denom + 1e-16f);
#pragma unroll
  for (int c = 0; c < CPL; ++c) {
    float v = acc[c] * inv + bias[h2 * C + cb + c];
    if (RELU) v = fmaxf(v, 0.f);
    out[(size_t)n * HC + h2 * C + cb + c] = v;
  }
}

// ============================ launch ============================
extern "C" void kernel_launch(void* const* d_in, const int* in_sizes, int n_in,
                              void* d_out, int out_size, void* d_ws, size_t ws_size,
                              hipStream_t stream) {
  const float* x    = (const float*)d_in[0];
  const int*   ei   = (const int*)d_in[1];
  const float* W0   = (const float*)d_in[2];
  const float* asr0 = (const float*)d_in[3];
  const float* adt0 = (const float*)d_in[4];
  const float* b0   = (const float*)d_in[5];
  const float* W1   = (const float*)d_in[6];
  const float* asr1 = (const float*)d_in[7];
  const float* adt1 = (const float*)d_in[8];
  const float* b1   = (const float*)d_in[9];
  const float* W2   = (const float*)d_in[10];
  const float* asr2 = (const float*)d_in[11];
  const float* adt2 = (const float*)d_in[12];
  const float* b2   = (const float*)d_in[13];

  const int FIN = 512, HID = 256, OUTC = 128;
  int N = in_sizes[0] / FIN;          // 20000
  int E = in_sizes[1] / 2;            // 320000
  int Etot = E + N;

  char* ws = (char*)d_ws;
  size_t off = 0;
  auto alloc = [&](size_t bytes) -> void* {
    void* p = ws + off;
    off = (off + bytes + 255) & ~(size_t)255;
    return p;
  };
  int* cnt       = (int*)alloc((size_t)N * 4);
  int* cursor    = (int*)alloc((size_t)N * 4);
  int* row_start = (int*)alloc((size_t)(N + 1) * 4);
  int* csr_src   = (int*)alloc((size_t)Etot * 4);
  float* as_     = (float*)alloc((size_t)N * 8 * 4);
  float* ad_     = (float*)alloc((size_t)N * 8 * 4);
  float* Hb      = (float*)alloc((size_t)N * HID * 4);                  // f32 C (layer 2 only)
  unsigned short* Hb16 = (unsigned short*)alloc((size_t)N * HID * 2);   // bf16 C mirror
  float* act     = (float*)alloc((size_t)N * HID * 4);                  // layer activation f32
  unsigned short* W0h = (unsigned short*)alloc((size_t)HID * FIN * 2);
  unsigned short* W0l = (unsigned short*)alloc((size_t)HID * FIN * 2);
  unsigned short* W1h = (unsigned short*)alloc((size_t)HID * HID * 2);
  unsigned short* W1l = (unsigned short*)alloc((size_t)HID * HID * 2);
  unsigned short* W2h = (unsigned short*)alloc((size_t)OUTC * HID * 2);
  unsigned short* W2l = (unsigned short*)alloc((size_t)OUTC * HID * 2);

  float* hpen = (float*)d_out;                       // [N, 256] f32
  float* out2 = (float*)d_out + (size_t)N * HID;     // [N, 128] f32

  // ---- presplit all weights (one launch) ----
  int n0_4 = HID * FIN / 4, n1_4 = HID * HID / 4, n2_4 = OUTC * HID / 4;
  int nsplit = n0_4 + n1_4 + n2_4;
  split3_kernel<<<(nsplit + 255) / 256, 256, 0, stream>>>(W0, W1, W2, W0h, W0l, W1h, W1l,
                                                          W2h, W2l, n0_4, n1_4, n2_4);

  // ---- CSR build (cnt+cursor are adjacent in ws: one memset spans both) ----
  (void)hipMemsetAsync(cnt, 0, (size_t)((char*)cursor - (char*)cnt) + (size_t)N * 4, stream);
  int eb = (Etot + 255) / 256;
  hist_kernel<<<eb, 256, 0, stream>>>(ei, E, N, cnt);
  scan_kernel<<<1, 1024, 0, stream>>>(cnt, row_start, N);
  scatter_kernel<<<eb, 256, 0, stream>>>(ei, E, N, row_start, cursor, csr_src);

  int mb = (N + 63) / 64;          // 313
  int mb8 = (mb + 7) / 8;          // 40
  int grid4 = 8 * 4 * mb8;         // NB=4 (HID=256)
  int grid2 = 8 * 2 * mb8;         // NB=2 (OUTC=128)

  // ---- layer 0: 512 -> 8x32, relu (alpha fused into GEMM) ----
  gemm_mfma<true, false><<<grid4, 256, 0, stream>>>(x, W0h, W0l, asr0, adt0, as_, ad_,
                                                    nullptr, Hb16, N, HID, FIN, 4);
  agg_kernel<8, 32, true><<<N, 64, 0, stream>>>(Hb16, as_, ad_, row_start, csr_src, b0,
                                                act, N);

  // ---- layer 1: 256 -> 8x32, relu (alpha fused; h_pen -> d_out f32) ----
  gemm_mfma<true, false><<<grid4, 256, 0, stream>>>(act, W1h, W1l, asr1, adt1, as_, ad_,
                                                    nullptr, Hb16, N, HID, HID, 4);
  agg_kernel<8, 32, true><<<N, 64, 0, stream>>>(Hb16, as_, ad_, row_start, csr_src, b1,
                                                hpen, N);

  // ---- layer 2: 256 -> 128, 1 head, no relu (standalone alpha on f32 C) ----
  gemm_mfma<false, true><<<grid2, 256, 0, stream>>>(hpen, W2h, W2l, nullptr, nullptr,
                                                    nullptr, nullptr, Hb, Hb16,
                                                    N, OUTC, HID, 2);
  alpha_kernel<1, 128><<<N, 64, 0, stream>>>(Hb, asr2, adt2, as_, ad_, N);
  agg_kernel<1, 128, false><<<N, 64, 0, stream>>>(Hb16, as_, ad_, row_start, csr_src, b2,
                                                  out2, N);
}

// Round 19
// 230.628 us; speedup vs baseline: 1.1131x; 1.0099x over previous
//
#include <hip/hip_runtime.h>
#include <hip/hip_bf16.h>

// d_out is FLOAT32. h_pen = first N*256 f32, h = next N*128 f32.

using bf16 = __hip_bfloat16;

typedef __attribute__((ext_vector_type(8))) short bf16x8;
typedef __attribute__((ext_vector_type(4))) short short4v;
typedef __attribute__((ext_vector_type(4))) float f32x4;
typedef __attribute__((ext_vector_type(2))) float f32x2;
typedef __attribute__((ext_vector_type(2))) unsigned int uint2v;

__device__ __forceinline__ float u2f(unsigned u) { union { float f; unsigned u; } c; c.u = u; return c.f; }
__device__ __forceinline__ unsigned f2u(float x) { union { float f; unsigned u; } c; c.f = x; return c.u; }
__device__ __forceinline__ short bfbits(float x) {
  unsigned xu = f2u(x);
  return (short)((xu + 0x7FFF + ((xu >> 16) & 1)) >> 16);
}

// ============================ CSR build (dst-sorted) ============================
__global__ void hist_kernel(const int* __restrict__ ei, int E, int N, int* __restrict__ cnt) {
  int e = blockIdx.x * 256 + threadIdx.x;
  if (e >= E + N) return;
  int dst = (e < E) ? ei[E + e] : (e - E);
  atomicAdd(&cnt[dst], 1);
}

__global__ __launch_bounds__(1024) void scan_kernel(const int* __restrict__ cnt,
                                                    int* __restrict__ row_start, int N) {
  __shared__ int part[1024];
  int t = threadIdx.x;
  int chunk = (N + 1023) / 1024;
  int lo = t * chunk; if (lo > N) lo = N;
  int hi = lo + chunk; if (hi > N) hi = N;
  int s = 0;
  for (int i = lo; i < hi; ++i) s += cnt[i];
  part[t] = s;
  __syncthreads();
  for (int off = 1; off < 1024; off <<= 1) {
    int add = (t >= off) ? part[t - off] : 0;
    __syncthreads();
    part[t] += add;
    __syncthreads();
  }
  int run = part[t] - s;
  for (int i = lo; i < hi; ++i) { row_start[i] = run; run += cnt[i]; }
  if (t == 1023) row_start[N] = part[1023];
}

__global__ void scatter_kernel(const int* __restrict__ ei, int E, int N,
                               const int* __restrict__ row_start, int* __restrict__ cursor,
                               int* __restrict__ csr_src) {
  int e = blockIdx.x * 256 + threadIdx.x;
  if (e >= E + N) return;
  int src, dst;
  if (e < E) { src = ei[e]; dst = ei[E + e]; }
  else       { src = e - E; dst = e - E; }
  int pos = atomicAdd(&cursor[dst], 1);
  csr_src[row_start[dst] + pos] = src;
}

// ============================ fused weight presplit (all 3 weights, one launch) ============================
__global__ void split3_kernel(const float* __restrict__ W0, const float* __restrict__ W1,
                              const float* __restrict__ W2,
                              unsigned short* __restrict__ W0h, unsigned short* __restrict__ W0l,
                              unsigned short* __restrict__ W1h, unsigned short* __restrict__ W1l,
                              unsigned short* __restrict__ W2h, unsigned short* __restrict__ W2l,
                              int n0_4, int n1_4, int n2_4) {
  int i = blockIdx.x * 256 + threadIdx.x;
  const float* in; unsigned short *hi, *lo; int idx;
  if (i < n0_4)                { in = W0; hi = W0h; lo = W0l; idx = i; }
  else if (i < n0_4 + n1_4)    { in = W1; hi = W1h; lo = W1l; idx = i - n0_4; }
  else if (i < n0_4 + n1_4 + n2_4) { in = W2; hi = W2h; lo = W2l; idx = i - n0_4 - n1_4; }
  else return;
  f32x4 v = *(const f32x4*)(in + (size_t)idx * 4);
  short4v h, l;
#pragma unroll
  for (int k = 0; k < 4; ++k) {
    short hb = bfbits(v[k]);
    h[k] = hb;
    l[k] = bfbits(v[k] - u2f(((unsigned)(unsigned short)hb) << 16));
  }
  *(short4v*)(hi + (size_t)idx * 4) = h;
  *(short4v*)(lo + (size_t)idx * 4) = l;
}

// ============================ MFMA GEMM 64x64, reg-prefetch pipeline + fused alpha ============================
#define LDP 40  // LDS pitch in shorts (80B: 16B-aligned, breaks pow2 stride)

__device__ __forceinline__ bf16x8 make_frag(const short* S, int row, int g) {
  short4v klo = *(const short4v*)&S[row * LDP + g * 4];
  short4v khi = *(const short4v*)&S[row * LDP + 16 + g * 4];
  bf16x8 r;
#pragma unroll
  for (int i = 0; i < 4; ++i) { r[i] = klo[i]; r[i + 4] = khi[i]; }
  return r;
}

template <bool FUSE8, bool WF32>
__global__ __launch_bounds__(256) void gemm_mfma(const float* __restrict__ Af,
                                                 const unsigned short* __restrict__ Bhg,
                                                 const unsigned short* __restrict__ Blg,
                                                 const float* __restrict__ Asrc,
                                                 const float* __restrict__ Adst,
                                                 float* __restrict__ as_,
                                                 float* __restrict__ ad_,
                                                 float* __restrict__ C,
                                                 unsigned short* __restrict__ C16,
                                                 int M, int Nn, int K, int NB) {
  // XCD-aware: same-bm blocks differ by 8 in id -> same XCD -> A panel L2 reuse.
  int id = blockIdx.x;
  int r8 = id & 7;
  int q  = id >> 3;
  int bn = q % NB;
  int bm = r8 + 8 * (q / NB);
  if (bm * 64 >= M) return;

  __shared__ short Ah[64 * LDP];
  __shared__ short Al[64 * LDP];
  __shared__ short Bh[64 * LDP];
  __shared__ short Bl[64 * LDP];
  int t = threadIdx.x;
  int w = t >> 6, l = t & 63;
  int g = l >> 4, lr = l & 15;

  f32x4 acc[4];
#pragma unroll
  for (int j = 0; j < 4; ++j) acc[j] = (f32x4)(0.f);

  int srow = t >> 2;            // 0..63
  int sseg = (t & 3) * 8;       // 0,8,16,24
  int gm = bm * 64 + srow;
  int gn = bn * 64 + srow;
  const float* Abase = Af + (size_t)gm * K + sseg;
  const unsigned short* Bhb = Bhg + (size_t)gn * K + sseg;
  const unsigned short* Blb = Blg + (size_t)gn * K + sseg;

  // ---- prologue: load iteration 0 into registers ----
  f32x4 va0 = (f32x4)(0.f), va1 = (f32x4)(0.f);
  int4 vbh, vbl;
  vbh = *(const int4*)(Bhb);
  vbl = *(const int4*)(Blb);
  if (gm < M) { va0 = *(const f32x4*)(Abase); va1 = *(const f32x4*)(Abase + 4); }

  for (int kt = 0; kt < K; kt += 32) {
    // ---- split current A regs (pre-barrier VALU, overlaps other waves' MFMA) ----
    short4v h0, l0, h1, l1;
#pragma unroll
    for (int i = 0; i < 4; ++i) {
      short hb0 = bfbits(va0[i]);
      l0[i] = bfbits(va0[i] - u2f(((unsigned)(unsigned short)hb0) << 16));
      h0[i] = hb0;
      short hb1 = bfbits(va1[i]);
      l1[i] = bfbits(va1[i] - u2f(((unsigned)(unsigned short)hb1) << 16));
      h1[i] = hb1;
    }
    __syncthreads();
    *(int4*)&Bh[srow * LDP + sseg] = vbh;
    *(int4*)&Bl[srow * LDP + sseg] = vbl;
    *(short4v*)&Ah[srow * LDP + sseg]     = h0;
    *(short4v*)&Ah[srow * LDP + sseg + 4] = h1;
    *(short4v*)&Al[srow * LDP + sseg]     = l0;
    *(short4v*)&Al[srow * LDP + sseg + 4] = l1;
    __syncthreads();

    // ---- prefetch iteration kt+32 (overlaps with MFMA below) ----
    if (kt + 32 < K) {
      int k2 = kt + 32;
      vbh = *(const int4*)(Bhb + k2);
      vbl = *(const int4*)(Blb + k2);
      if (gm < M) { va0 = *(const f32x4*)(Abase + k2); va1 = *(const f32x4*)(Abase + k2 + 4); }
    }

    // ---- fragments + MFMA ----
    int arow = w * 16 + lr;
    bf16x8 ah = make_frag(Ah, arow, g);
    bf16x8 al = make_frag(Al, arow, g);
#pragma unroll
    for (int j = 0; j < 4; ++j) {
      int brow = j * 16 + lr;
      bf16x8 bh = make_frag(Bh, brow, g);
      bf16x8 bl = make_frag(Bl, brow, g);
      acc[j] = __builtin_amdgcn_mfma_f32_16x16x32_bf16(ah, bh, acc[j], 0, 0, 0);
      acc[j] = __builtin_amdgcn_mfma_f32_16x16x32_bf16(al, bh, acc[j], 0, 0, 0);
      acc[j] = __builtin_amdgcn_mfma_f32_16x16x32_bf16(ah, bl, acc[j], 0, 0, 0);
    }
  }

  // ---- C write. C/D layout (HW-verified m89): col = lane&15, row = (lane>>4)*4 + reg ----
#pragma unroll
  for (int j = 0; j < 4; ++j) {
#pragma unroll
    for (int r = 0; r < 4; ++r) {
      int row = bm * 64 + w * 16 + g * 4 + r;
      int col = bn * 64 + j * 16 + lr;
      if (row < M) {
        float v = acc[j][r];
        if constexpr (WF32) C[(size_t)row * Nn + col] = v;
        C16[(size_t)row * Nn + col] = (unsigned short)bfbits(v);
      }
    }
  }

  // ---- fused alpha epilogue (H=8, C=32): block covers heads 2bn, 2bn+1 ----
  if constexpr (FUSE8) {
    float cs[4], cd[4];
#pragma unroll
    for (int j = 0; j < 4; ++j) {
      cs[j] = Asrc[bn * 64 + j * 16 + lr];
      cd[j] = Adst[bn * 64 + j * 16 + lr];
    }
#pragma unroll
    for (int r = 0; r < 4; ++r) {
      float sA0 = acc[0][r] * cs[0] + acc[1][r] * cs[1];   // head 2bn
      float sA1 = acc[2][r] * cs[2] + acc[3][r] * cs[3];   // head 2bn+1
      float sD0 = acc[0][r] * cd[0] + acc[1][r] * cd[1];
      float sD1 = acc[2][r] * cd[2] + acc[3][r] * cd[3];
#pragma unroll
      for (int mask = 1; mask < 16; mask <<= 1) {
        sA0 += __shfl_xor(sA0, mask);
        sA1 += __shfl_xor(sA1, mask);
        sD0 += __shfl_xor(sD0, mask);
        sD1 += __shfl_xor(sD1, mask);
      }
      if (lr == 0) {
        int row = bm * 64 + w * 16 + g * 4 + r;
        if (row < M) {
          as_[row * 8 + bn * 2]     = sA0;
          as_[row * 8 + bn * 2 + 1] = sA1;
          ad_[row * 8 + bn * 2]     = sD0;
          ad_[row * 8 + bn * 2 + 1] = sD1;
        }
      }
    }
  }
}

// ============================ alpha projection (layer 2 only: H=1, C=128) ============================
template <int H, int C>
__global__ __launch_bounds__(64) void alpha_kernel(const float* __restrict__ Hb,
                                                   const float* __restrict__ a_src,
                                                   const float* __restrict__ a_dst,
                                                   float* __restrict__ as_,
                                                   float* __restrict__ ad_, int N) {
  constexpr int HC = H * C;
  constexpr int EPL = HC / 64;
  constexpr int LPH = 64 / H;
  int n = blockIdx.x;
  int l = threadIdx.x;
  const float* row = Hb + (size_t)n * HC + l * EPL;
  float s1 = 0.f, s2 = 0.f;
  if constexpr (EPL == 4) {
    f32x4 v = *(const f32x4*)row;
    f32x4 a1 = *(const f32x4*)(a_src + l * 4);
    f32x4 a2 = *(const f32x4*)(a_dst + l * 4);
#pragma unroll
    for (int k = 0; k < 4; ++k) { s1 += v[k] * a1[k]; s2 += v[k] * a2[k]; }
  } else {
    f32x2 v = *(const f32x2*)row;
    f32x2 a1 = *(const f32x2*)(a_src + l * 2);
    f32x2 a2 = *(const f32x2*)(a_dst + l * 2);
#pragma unroll
    for (int k = 0; k < 2; ++k) { s1 += v[k] * a1[k]; s2 += v[k] * a2[k]; }
  }
#pragma unroll
  for (int mask = 1; mask < LPH; mask <<= 1) {
    s1 += __shfl_xor(s1, mask);
    s2 += __shfl_xor(s2, mask);
  }
  if ((l & (LPH - 1)) == 0) {
    int h = l / LPH;
    as_[n * H + h] = s1;
    ad_[n * H + h] = s2;
  }
}

// ============================ softmax + aggregate (bf16 gather, 2-way unroll) ============================
template <int H, int C, bool RELU>
__global__ __launch_bounds__(64) void agg_kernel(const unsigned short* __restrict__ Hb16,
                                                 const float* __restrict__ as_,
                                                 const float* __restrict__ ad_,
                                                 const int* __restrict__ row_start,
                                                 const int* __restrict__ csr_src,
                                                 const float* __restrict__ bias,
                                                 float* __restrict__ out, int N) {
  int n = blockIdx.x;
  if (n >= N) return;
  int l = threadIdx.x;
  int s = row_start[n], e = row_start[n + 1];

  constexpr int LPH = 64 / H;
  constexpr int CPL = C / LPH;
  constexpr int HC = H * C;
  int h2 = l / LPH;
  int cb = (l % LPH) * CPL;
  float ad2 = ad_[n * H + h2];

  float acc[CPL];
#pragma unroll
  for (int c = 0; c < CPL; ++c) acc[c] = 0.f;
  float denom = 0.f;

  int j = s;
  for (; j + 1 < e; j += 2) {
    int s0 = csr_src[j], s1v = csr_src[j + 1];
    float x0 = as_[s0 * H + h2] + ad2;
    float x1 = as_[s1v * H + h2] + ad2;
    x0 = x0 > 0.f ? x0 : 0.2f * x0;
    x1 = x1 > 0.f ? x1 : 0.2f * x1;
    float p0 = __expf(x0), p1 = __expf(x1);
    denom += p0 + p1;
    const unsigned short* hp0 = Hb16 + (size_t)s0 * HC + h2 * C + cb;
    const unsigned short* hp1 = Hb16 + (size_t)s1v * HC + h2 * C + cb;
    if constexpr (CPL == 4) {
      uint2v u0 = *(const uint2v*)hp0;
      uint2v u1 = *(const uint2v*)hp1;
#pragma unroll
      for (int c = 0; c < 2; ++c) {
        acc[2 * c]     += p0 * u2f(u0[c] << 16)         + p1 * u2f(u1[c] << 16);
        acc[2 * c + 1] += p0 * u2f(u0[c] & 0xFFFF0000u) + p1 * u2f(u1[c] & 0xFFFF0000u);
      }
    } else {
      unsigned u0 = *(const unsigned*)hp0;
      unsigned u1 = *(const unsigned*)hp1;
      acc[0] += p0 * u2f(u0 << 16)         + p1 * u2f(u1 << 16);
      acc[1] += p0 * u2f(u0 & 0xFFFF0000u) + p1 * u2f(u1 & 0xFFFF0000u);
    }
  }
  if (j < e) {
    int s0 = csr_src[j];
    float x0 = as_[s0 * H + h2] + ad2;
    x0 = x0 > 0.f ? x0 : 0.2f * x0;
    float p0 = __expf(x0);
    denom += p0;
    const unsigned short* hp0 = Hb16 + (size_t)s0 * HC + h2 * C + cb;
    if constexpr (CPL == 4) {
      uint2v u0 = *(const uint2v*)hp0;
#pragma unroll
      for (int c = 0; c < 2; ++c) {
        acc[2 * c]     += p0 * u2f(u0[c] << 16);
        acc[2 * c + 1] += p0 * u2f(u0[c] & 0xFFFF0000u);
      }
    } else {
      unsigned u0 = *(const unsigned*)hp0;
      acc[0] += p0 * u2f(u0 << 16);
      acc[1] += p0 * u2f(u0 & 0xFFFF0000u);
    }
  }

  float inv = 1.f / (denom + 1e-16f);
#pragma unroll
  for (int c = 0; c < CPL; ++c) {
    float v = acc[c] * inv + bias[h2 * C + cb + c];
    if (RELU) v = fmaxf(v, 0.f);
    out[(size_t)n * HC + h2 * C + cb + c] = v;
  }
}

// ============================ launch ============================
extern "C" void kernel_launch(void* const* d_in, const int* in_sizes, int n_in,
                              void* d_out, int out_size, void* d_ws, size_t ws_size,
                              hipStream_t stream) {
  const float* x    = (const float*)d_in[0];
  const int*   ei   = (const int*)d_in[1];
  const float* W0   = (const float*)d_in[2];
  const float* asr0 = (const float*)d_in[3];
  const float* adt0 = (const float*)d_in[4];
  const float* b0   = (const float*)d_in[5];
  const float* W1   = (const float*)d_in[6];
  const float* asr1 = (const float*)d_in[7];
  const float* adt1 = (const float*)d_in[8];
  const float* b1   = (const float*)d_in[9];
  const float* W2   = (const float*)d_in[10];
  const float* asr2 = (const float*)d_in[11];
  const float* adt2 = (const float*)d_in[12];
  const float* b2   = (const float*)d_in[13];

  const int FIN = 512, HID = 256, OUTC = 128;
  int N = in_sizes[0] / FIN;          // 20000
  int E = in_sizes[1] / 2;            // 320000
  int Etot = E + N;

  char* ws = (char*)d_ws;
  size_t off = 0;
  auto alloc = [&](size_t bytes) -> void* {
    void* p = ws + off;
    off = (off + bytes + 255) & ~(size_t)255;
    return p;
  };
  int* cnt       = (int*)alloc((size_t)N * 4);
  int* cursor    = (int*)alloc((size_t)N * 4);
  int* row_start = (int*)alloc((size_t)(N + 1) * 4);
  int* csr_src   = (int*)alloc((size_t)Etot * 4);
  float* as_     = (float*)alloc((size_t)N * 8 * 4);
  float* ad_     = (float*)alloc((size_t)N * 8 * 4);
  float* Hb      = (float*)alloc((size_t)N * HID * 4);                  // f32 C (layer 2 only)
  unsigned short* Hb16 = (unsigned short*)alloc((size_t)N * HID * 2);   // bf16 C mirror
  float* act     = (float*)alloc((size_t)N * HID * 4);                  // layer activation f32
  unsigned short* W0h = (unsigned short*)alloc((size_t)HID * FIN * 2);
  unsigned short* W0l = (unsigned short*)alloc((size_t)HID * FIN * 2);
  unsigned short* W1h = (unsigned short*)alloc((size_t)HID * HID * 2);
  unsigned short* W1l = (unsigned short*)alloc((size_t)HID * HID * 2);
  unsigned short* W2h = (unsigned short*)alloc((size_t)OUTC * HID * 2);
  unsigned short* W2l = (unsigned short*)alloc((size_t)OUTC * HID * 2);

  float* hpen = (float*)d_out;                       // [N, 256] f32
  float* out2 = (float*)d_out + (size_t)N * HID;     // [N, 128] f32

  // ---- presplit all weights (one launch) ----
  int n0_4 = HID * FIN / 4, n1_4 = HID * HID / 4, n2_4 = OUTC * HID / 4;
  int nsplit = n0_4 + n1_4 + n2_4;
  split3_kernel<<<(nsplit + 255) / 256, 256, 0, stream>>>(W0, W1, W2, W0h, W0l, W1h, W1l,
                                                          W2h, W2l, n0_4, n1_4, n2_4);

  // ---- CSR build (cnt+cursor adjacent: one memset spans both) ----
  (void)hipMemsetAsync(cnt, 0, (size_t)((char*)cursor - (char*)cnt) + (size_t)N * 4, stream);
  int eb = (Etot + 255) / 256;
  hist_kernel<<<eb, 256, 0, stream>>>(ei, E, N, cnt);
  scan_kernel<<<1, 1024, 0, stream>>>(cnt, row_start, N);
  scatter_kernel<<<eb, 256, 0, stream>>>(ei, E, N, row_start, cursor, csr_src);

  int mb = (N + 63) / 64;          // 313
  int mb8 = (mb + 7) / 8;          // 40
  int grid4 = 8 * 4 * mb8;         // NB=4 (HID=256)
  int grid2 = 8 * 2 * mb8;         // NB=2 (OUTC=128)

  // ---- layer 0: 512 -> 8x32, relu (alpha fused into GEMM) ----
  gemm_mfma<true, false><<<grid4, 256, 0, stream>>>(x, W0h, W0l, asr0, adt0, as_, ad_,
                                                    nullptr, Hb16, N, HID, FIN, 4);
  agg_kernel<8, 32, true><<<N, 64, 0, stream>>>(Hb16, as_, ad_, row_start, csr_src, b0,
                                                act, N);

  // ---- layer 1: 256 -> 8x32, relu (alpha fused; h_pen -> d_out f32) ----
  gemm_mfma<true, false><<<grid4, 256, 0, stream>>>(act, W1h, W1l, asr1, adt1, as_, ad_,
                                                    nullptr, Hb16, N, HID, HID, 4);
  agg_kernel<8, 32, true><<<N, 64, 0, stream>>>(Hb16, as_, ad_, row_start, csr_src, b1,
                                                hpen, N);

  // ---- layer 2: 256 -> 128, 1 head, no relu (standalone alpha on f32 C) ----
  gemm_mfma<false, true><<<grid2, 256, 0, stream>>>(hpen, W2h, W2l, nullptr, nullptr,
                                                    nullptr, nullptr, Hb, Hb16,
                                                    N, OUTC, HID, 2);
  alpha_kernel<1, 128><<<N, 64, 0, stream>>>(Hb, asr2, adt2, as_, ad_, N);
  agg_kernel<1, 128, false><<<N, 64, 0, stream>>>(Hb16, as_, ad_, row_start, csr_src, b2,
                                                  out2, N);
}

// Round 20
// 223.508 us; speedup vs baseline: 1.1486x; 1.0319x over previous
//
#include <hip/hip_runtime.h>
#include <hip/hip_bf16.h>

// d_out is FLOAT32. h_pen = first N*256 f32, h = next N*128 f32.

using bf16 = __hip_bfloat16;

typedef __attribute__((ext_vector_type(8))) short bf16x8;
typedef __attribute__((ext_vector_type(4))) short short4v;
typedef __attribute__((ext_vector_type(4))) float f32x4;
typedef __attribute__((ext_vector_type(2))) float f32x2;
typedef __attribute__((ext_vector_type(2))) unsigned int uint2v;

__device__ __forceinline__ float u2f(unsigned u) { union { float f; unsigned u; } c; c.u = u; return c.f; }
__device__ __forceinline__ unsigned f2u(float x) { union { float f; unsigned u; } c; c.f = x; return c.u; }
__device__ __forceinline__ short bfbits(float x) {
  unsigned xu = f2u(x);
  return (short)((xu + 0x7FFF + ((xu >> 16) & 1)) >> 16);
}

// ============================ CSR build (dst-sorted) ============================
__global__ void hist_kernel(const int* __restrict__ ei, int E, int N, int* __restrict__ cnt) {
  int e = blockIdx.x * 256 + threadIdx.x;
  if (e >= E + N) return;
  int dst = (e < E) ? ei[E + e] : (e - E);
  atomicAdd(&cnt[dst], 1);
}

__global__ __launch_bounds__(1024) void scan_kernel(const int* __restrict__ cnt,
                                                    int* __restrict__ row_start, int N) {
  __shared__ int part[1024];
  int t = threadIdx.x;
  int chunk = (N + 1023) / 1024;
  int lo = t * chunk; if (lo > N) lo = N;
  int hi = lo + chunk; if (hi > N) hi = N;
  int s = 0;
  for (int i = lo; i < hi; ++i) s += cnt[i];
  part[t] = s;
  __syncthreads();
  for (int off = 1; off < 1024; off <<= 1) {
    int add = (t >= off) ? part[t - off] : 0;
    __syncthreads();
    part[t] += add;
    __syncthreads();
  }
  int run = part[t] - s;
  for (int i = lo; i < hi; ++i) { row_start[i] = run; run += cnt[i]; }
  if (t == 1023) row_start[N] = part[1023];
}

__global__ void scatter_kernel(const int* __restrict__ ei, int E, int N,
                               const int* __restrict__ row_start, int* __restrict__ cursor,
                               int* __restrict__ csr_src) {
  int e = blockIdx.x * 256 + threadIdx.x;
  if (e >= E + N) return;
  int src, dst;
  if (e < E) { src = ei[e]; dst = ei[E + e]; }
  else       { src = e - E; dst = e - E; }
  int pos = atomicAdd(&cursor[dst], 1);
  csr_src[row_start[dst] + pos] = src;
}

// ============================ fused weight presplit (all 3 weights, one launch) ============================
__global__ void split3_kernel(const float* __restrict__ W0, const float* __restrict__ W1,
                              const float* __restrict__ W2,
                              unsigned short* __restrict__ W0h, unsigned short* __restrict__ W0l,
                              unsigned short* __restrict__ W1h, unsigned short* __restrict__ W1l,
                              unsigned short* __restrict__ W2h, unsigned short* __restrict__ W2l,
                              int n0_4, int n1_4, int n2_4) {
  int i = blockIdx.x * 256 + threadIdx.x;
  const float* in; unsigned short *hi, *lo; int idx;
  if (i < n0_4)                { in = W0; hi = W0h; lo = W0l; idx = i; }
  else if (i < n0_4 + n1_4)    { in = W1; hi = W1h; lo = W1l; idx = i - n0_4; }
  else if (i < n0_4 + n1_4 + n2_4) { in = W2; hi = W2h; lo = W2l; idx = i - n0_4 - n1_4; }
  else return;
  f32x4 v = *(const f32x4*)(in + (size_t)idx * 4);
  short4v h, l;
#pragma unroll
  for (int k = 0; k < 4; ++k) {
    short hb = bfbits(v[k]);
    h[k] = hb;
    l[k] = bfbits(v[k] - u2f(((unsigned)(unsigned short)hb) << 16));
  }
  *(short4v*)(hi + (size_t)idx * 4) = h;
  *(short4v*)(lo + (size_t)idx * 4) = l;
}

__global__ void zero_f32_kernel(float* __restrict__ p, int n) {
  int i = blockIdx.x * 256 + threadIdx.x;
  if (i < n) p[i] = 0.f;
}

// ============================ MFMA GEMM 64x64, reg-prefetch + fused alpha ============================
// FUSE8: H=8/C=32 alpha (block cols = heads 2bn,2bn+1), direct writes.
// FUSE1: H=1/C=128 alpha (partial 64-col dot, atomicAdd; as_/ad_ pre-zeroed).
#define LDP 40  // LDS pitch in shorts (80B: 16B-aligned, breaks pow2 stride)

__device__ __forceinline__ bf16x8 make_frag(const short* S, int row, int g) {
  short4v klo = *(const short4v*)&S[row * LDP + g * 4];
  short4v khi = *(const short4v*)&S[row * LDP + 16 + g * 4];
  bf16x8 r;
#pragma unroll
  for (int i = 0; i < 4; ++i) { r[i] = klo[i]; r[i + 4] = khi[i]; }
  return r;
}

template <bool FUSE8, bool FUSE1>
__global__ __launch_bounds__(256) void gemm_mfma(const float* __restrict__ Af,
                                                 const unsigned short* __restrict__ Bhg,
                                                 const unsigned short* __restrict__ Blg,
                                                 const float* __restrict__ Asrc,
                                                 const float* __restrict__ Adst,
                                                 float* __restrict__ as_,
                                                 float* __restrict__ ad_,
                                                 unsigned short* __restrict__ C16,
                                                 int M, int Nn, int K, int NB) {
  // XCD-aware: same-bm blocks differ by 8 in id -> same XCD -> A panel L2 reuse.
  int id = blockIdx.x;
  int r8 = id & 7;
  int q  = id >> 3;
  int bn = q % NB;
  int bm = r8 + 8 * (q / NB);
  if (bm * 64 >= M) return;

  __shared__ short Ah[64 * LDP];
  __shared__ short Al[64 * LDP];
  __shared__ short Bh[64 * LDP];
  __shared__ short Bl[64 * LDP];
  int t = threadIdx.x;
  int w = t >> 6, l = t & 63;
  int g = l >> 4, lr = l & 15;

  f32x4 acc[4];
#pragma unroll
  for (int j = 0; j < 4; ++j) acc[j] = (f32x4)(0.f);

  int srow = t >> 2;            // 0..63
  int sseg = (t & 3) * 8;       // 0,8,16,24
  int gm = bm * 64 + srow;
  int gn = bn * 64 + srow;
  const float* Abase = Af + (size_t)gm * K + sseg;
  const unsigned short* Bhb = Bhg + (size_t)gn * K + sseg;
  const unsigned short* Blb = Blg + (size_t)gn * K + sseg;

  // ---- prologue: load iteration 0 ----
  f32x4 va0 = (f32x4)(0.f), va1 = (f32x4)(0.f);
  int4 vbh = *(const int4*)(Bhb);
  int4 vbl = *(const int4*)(Blb);
  if (gm < M) { va0 = *(const f32x4*)(Abase); va1 = *(const f32x4*)(Abase + 4); }

  for (int kt = 0; kt < K; kt += 32) {
    short4v h0, l0, h1, l1;
#pragma unroll
    for (int i = 0; i < 4; ++i) {
      short hb0 = bfbits(va0[i]);
      l0[i] = bfbits(va0[i] - u2f(((unsigned)(unsigned short)hb0) << 16));
      h0[i] = hb0;
      short hb1 = bfbits(va1[i]);
      l1[i] = bfbits(va1[i] - u2f(((unsigned)(unsigned short)hb1) << 16));
      h1[i] = hb1;
    }
    __syncthreads();
    *(int4*)&Bh[srow * LDP + sseg] = vbh;
    *(int4*)&Bl[srow * LDP + sseg] = vbl;
    *(short4v*)&Ah[srow * LDP + sseg]     = h0;
    *(short4v*)&Ah[srow * LDP + sseg + 4] = h1;
    *(short4v*)&Al[srow * LDP + sseg]     = l0;
    *(short4v*)&Al[srow * LDP + sseg + 4] = l1;
    __syncthreads();

    if (kt + 32 < K) {
      int k2 = kt + 32;
      vbh = *(const int4*)(Bhb + k2);
      vbl = *(const int4*)(Blb + k2);
      if (gm < M) { va0 = *(const f32x4*)(Abase + k2); va1 = *(const f32x4*)(Abase + k2 + 4); }
    }

    int arow = w * 16 + lr;
    bf16x8 ah = make_frag(Ah, arow, g);
    bf16x8 al = make_frag(Al, arow, g);
#pragma unroll
    for (int j = 0; j < 4; ++j) {
      int brow = j * 16 + lr;
      bf16x8 bh = make_frag(Bh, brow, g);
      bf16x8 bl = make_frag(Bl, brow, g);
      acc[j] = __builtin_amdgcn_mfma_f32_16x16x32_bf16(ah, bh, acc[j], 0, 0, 0);
      acc[j] = __builtin_amdgcn_mfma_f32_16x16x32_bf16(al, bh, acc[j], 0, 0, 0);
      acc[j] = __builtin_amdgcn_mfma_f32_16x16x32_bf16(ah, bl, acc[j], 0, 0, 0);
    }
  }

  // ---- C16 write. C/D layout (HW-verified m89): col = lane&15, row = (lane>>4)*4 + reg ----
#pragma unroll
  for (int j = 0; j < 4; ++j) {
#pragma unroll
    for (int r = 0; r < 4; ++r) {
      int row = bm * 64 + w * 16 + g * 4 + r;
      int col = bn * 64 + j * 16 + lr;
      if (row < M) C16[(size_t)row * Nn + col] = (unsigned short)bfbits(acc[j][r]);
    }
  }

  // ---- fused alpha (H=8): block covers heads 2bn, 2bn+1 ----
  if constexpr (FUSE8) {
    float cs[4], cd[4];
#pragma unroll
    for (int j = 0; j < 4; ++j) {
      cs[j] = Asrc[bn * 64 + j * 16 + lr];
      cd[j] = Adst[bn * 64 + j * 16 + lr];
    }
#pragma unroll
    for (int r = 0; r < 4; ++r) {
      float sA0 = acc[0][r] * cs[0] + acc[1][r] * cs[1];
      float sA1 = acc[2][r] * cs[2] + acc[3][r] * cs[3];
      float sD0 = acc[0][r] * cd[0] + acc[1][r] * cd[1];
      float sD1 = acc[2][r] * cd[2] + acc[3][r] * cd[3];
#pragma unroll
      for (int mask = 1; mask < 16; mask <<= 1) {
        sA0 += __shfl_xor(sA0, mask);
        sA1 += __shfl_xor(sA1, mask);
        sD0 += __shfl_xor(sD0, mask);
        sD1 += __shfl_xor(sD1, mask);
      }
      if (lr == 0) {
        int row = bm * 64 + w * 16 + g * 4 + r;
        if (row < M) {
          as_[row * 8 + bn * 2]     = sA0;
          as_[row * 8 + bn * 2 + 1] = sA1;
          ad_[row * 8 + bn * 2]     = sD0;
          ad_[row * 8 + bn * 2 + 1] = sD1;
        }
      }
    }
  }

  // ---- fused alpha (H=1, C=128): partial 64-col dot, atomicAdd (pre-zeroed) ----
  if constexpr (FUSE1) {
    float cs[4], cd[4];
#pragma unroll
    for (int j = 0; j < 4; ++j) {
      cs[j] = Asrc[bn * 64 + j * 16 + lr];
      cd[j] = Adst[bn * 64 + j * 16 + lr];
    }
#pragma unroll
    for (int r = 0; r < 4; ++r) {
      float sA = acc[0][r] * cs[0] + acc[1][r] * cs[1] + acc[2][r] * cs[2] + acc[3][r] * cs[3];
      float sD = acc[0][r] * cd[0] + acc[1][r] * cd[1] + acc[2][r] * cd[2] + acc[3][r] * cd[3];
#pragma unroll
      for (int mask = 1; mask < 16; mask <<= 1) {
        sA += __shfl_xor(sA, mask);
        sD += __shfl_xor(sD, mask);
      }
      if (lr == 0) {
        int row = bm * 64 + w * 16 + g * 4 + r;
        if (row < M) {
          atomicAdd(&as_[row], sA);
          atomicAdd(&ad_[row], sD);
        }
      }
    }
  }
}

// ============================ softmax + aggregate (bf16 gather, 4-deep) ============================
template <int H, int C, bool RELU>
__global__ __launch_bounds__(64) void agg_kernel(const unsigned short* __restrict__ Hb16,
                                                 const float* __restrict__ as_,
                                                 const float* __restrict__ ad_,
                                                 const int* __restrict__ row_start,
                                                 const int* __restrict__ csr_src,
                                                 const float* __restrict__ bias,
                                                 float* __restrict__ out, int N) {
  int n = blockIdx.x;
  if (n >= N) return;
  int l = threadIdx.x;
  int s = row_start[n], e = row_start[n + 1];

  constexpr int LPH = 64 / H;
  constexpr int CPL = C / LPH;
  constexpr int HC = H * C;
  int h2 = l / LPH;
  int cb = (l % LPH) * CPL;
  float ad2 = ad_[n * H + h2];

  float acc[CPL];
#pragma unroll
  for (int c = 0; c < CPL; ++c) acc[c] = 0.f;
  float denom = 0.f;

  auto lrelu = [](float x) { return x > 0.f ? x : 0.2f * x; };

  int j = s;
  for (; j + 3 < e; j += 4) {
    int s0 = csr_src[j], s1 = csr_src[j + 1], s2 = csr_src[j + 2], s3 = csr_src[j + 3];
    float x0 = as_[s0 * H + h2], x1 = as_[s1 * H + h2];
    float x2 = as_[s2 * H + h2], x3 = as_[s3 * H + h2];
    const unsigned short* hp0 = Hb16 + (size_t)s0 * HC + h2 * C + cb;
    const unsigned short* hp1 = Hb16 + (size_t)s1 * HC + h2 * C + cb;
    const unsigned short* hp2 = Hb16 + (size_t)s2 * HC + h2 * C + cb;
    const unsigned short* hp3 = Hb16 + (size_t)s3 * HC + h2 * C + cb;
    float p0 = __expf(lrelu(x0 + ad2)), p1 = __expf(lrelu(x1 + ad2));
    float p2 = __expf(lrelu(x2 + ad2)), p3 = __expf(lrelu(x3 + ad2));
    denom += (p0 + p1) + (p2 + p3);
    if constexpr (CPL == 4) {
      uint2v u0 = *(const uint2v*)hp0;
      uint2v u1 = *(const uint2v*)hp1;
      uint2v u2 = *(const uint2v*)hp2;
      uint2v u3 = *(const uint2v*)hp3;
#pragma unroll
      for (int c = 0; c < 2; ++c) {
        acc[2 * c]     += p0 * u2f(u0[c] << 16)         + p1 * u2f(u1[c] << 16)
                        + p2 * u2f(u2[c] << 16)         + p3 * u2f(u3[c] << 16);
        acc[2 * c + 1] += p0 * u2f(u0[c] & 0xFFFF0000u) + p1 * u2f(u1[c] & 0xFFFF0000u)
                        + p2 * u2f(u2[c] & 0xFFFF0000u) + p3 * u2f(u3[c] & 0xFFFF0000u);
      }
    } else {
      unsigned u0 = *(const unsigned*)hp0;
      unsigned u1 = *(const unsigned*)hp1;
      unsigned u2 = *(const unsigned*)hp2;
      unsigned u3 = *(const unsigned*)hp3;
      acc[0] += p0 * u2f(u0 << 16)         + p1 * u2f(u1 << 16)
              + p2 * u2f(u2 << 16)         + p3 * u2f(u3 << 16);
      acc[1] += p0 * u2f(u0 & 0xFFFF0000u) + p1 * u2f(u1 & 0xFFFF0000u)
              + p2 * u2f(u2 & 0xFFFF0000u) + p3 * u2f(u3 & 0xFFFF0000u);
    }
  }
  for (; j < e; ++j) {
    int s0 = csr_src[j];
    float p0 = __expf(lrelu(as_[s0 * H + h2] + ad2));
    denom += p0;
    const unsigned short* hp0 = Hb16 + (size_t)s0 * HC + h2 * C + cb;
    if constexpr (CPL == 4) {
      uint2v u0 = *(const uint2v*)hp0;
#pragma unroll
      for (int c = 0; c < 2; ++c) {
        acc[2 * c]     += p0 * u2f(u0[c] << 16);
        acc[2 * c + 1] += p0 * u2f(u0[c] & 0xFFFF0000u);
      }
    } else {
      unsigned u0 = *(const unsigned*)hp0;
      acc[0] += p0 * u2f(u0 << 16);
      acc[1] += p0 * u2f(u0 & 0xFFFF0000u);
    }
  }

  float inv = 1.f / (denom + 1e-16f);
#pragma unroll
  for (int c = 0; c < CPL; ++c) {
    float v = acc[c] * inv + bias[h2 * C + cb + c];
    if (RELU) v = fmaxf(v, 0.f);
    out[(size_t)n * HC + h2 * C + cb + c] = v;
  }
}

// ============================ launch ============================
extern "C" void kernel_launch(void* const* d_in, const int* in_sizes, int n_in,
                              void* d_out, int out_size, void* d_ws, size_t ws_size,
                              hipStream_t stream) {
  const float* x    = (const float*)d_in[0];
  const int*   ei   = (const int*)d_in[1];
  const float* W0   = (const float*)d_in[2];
  const float* asr0 = (const float*)d_in[3];
  const float* adt0 = (const float*)d_in[4];
  const float* b0   = (const float*)d_in[5];
  const float* W1   = (const float*)d_in[6];
  const float* asr1 = (const float*)d_in[7];
  const float* adt1 = (const float*)d_in[8];
  const float* b1   = (const float*)d_in[9];
  const float* W2   = (const float*)d_in[10];
  const float* asr2 = (const float*)d_in[11];
  const float* adt2 = (const float*)d_in[12];
  const float* b2   = (const float*)d_in[13];

  const int FIN = 512, HID = 256, OUTC = 128;
  int N = in_sizes[0] / FIN;          // 20000
  int E = in_sizes[1] / 2;            // 320000
  int Etot = E + N;

  char* ws = (char*)d_ws;
  size_t off = 0;
  auto alloc = [&](size_t bytes) -> void* {
    void* p = ws + off;
    off = (off + bytes + 255) & ~(size_t)255;
    return p;
  };
  int* cnt       = (int*)alloc((size_t)N * 4);
  int* cursor    = (int*)alloc((size_t)N * 4);
  int* row_start = (int*)alloc((size_t)(N + 1) * 4);
  int* csr_src   = (int*)alloc((size_t)Etot * 4);
  float* as_     = (float*)alloc((size_t)N * 8 * 4);
  float* ad_     = (float*)alloc((size_t)N * 8 * 4);
  unsigned short* Hb16 = (unsigned short*)alloc((size_t)N * HID * 2);   // bf16 C mirror
  float* act     = (float*)alloc((size_t)N * HID * 4);                  // layer activation f32
  unsigned short* W0h = (unsigned short*)alloc((size_t)HID * FIN * 2);
  unsigned short* W0l = (unsigned short*)alloc((size_t)HID * FIN * 2);
  unsigned short* W1h = (unsigned short*)alloc((size_t)HID * HID * 2);
  unsigned short* W1l = (unsigned short*)alloc((size_t)HID * HID * 2);
  unsigned short* W2h = (unsigned short*)alloc((size_t)OUTC * HID * 2);
  unsigned short* W2l = (unsigned short*)alloc((size_t)OUTC * HID * 2);

  float* hpen = (float*)d_out;                       // [N, 256] f32
  float* out2 = (float*)d_out + (size_t)N * HID;     // [N, 128] f32

  // ---- presplit all weights (one launch) ----
  int n0_4 = HID * FIN / 4, n1_4 = HID * HID / 4, n2_4 = OUTC * HID / 4;
  int nsplit = n0_4 + n1_4 + n2_4;
  split3_kernel<<<(nsplit + 255) / 256, 256, 0, stream>>>(W0, W1, W2, W0h, W0l, W1h, W1l,
                                                          W2h, W2l, n0_4, n1_4, n2_4);

  // ---- CSR build ----
  (void)hipMemsetAsync(cnt, 0, (size_t)((char*)cursor - (char*)cnt) + (size_t)N * 4, stream);
  int eb = (Etot + 255) / 256;
  hist_kernel<<<eb, 256, 0, stream>>>(ei, E, N, cnt);
  scan_kernel<<<1, 1024, 0, stream>>>(cnt, row_start, N);
  scatter_kernel<<<eb, 256, 0, stream>>>(ei, E, N, row_start, cursor, csr_src);

  int mb = (N + 63) / 64;          // 313
  int mb8 = (mb + 7) / 8;          // 40
  int grid4 = 8 * 4 * mb8;         // NB=4 (HID=256)
  int grid2 = 8 * 2 * mb8;         // NB=2 (OUTC=128)

  // ---- layer 0: 512 -> 8x32, relu (alpha fused) ----
  gemm_mfma<true, false><<<grid4, 256, 0, stream>>>(x, W0h, W0l, asr0, adt0, as_, ad_,
                                                    Hb16, N, HID, FIN, 4);
  agg_kernel<8, 32, true><<<N, 64, 0, stream>>>(Hb16, as_, ad_, row_start, csr_src, b0,
                                                act, N);

  // ---- layer 1: 256 -> 8x32, relu (alpha fused; h_pen -> d_out f32) ----
  gemm_mfma<true, false><<<grid4, 256, 0, stream>>>(act, W1h, W1l, asr1, adt1, as_, ad_,
                                                    Hb16, N, HID, HID, 4);
  agg_kernel<8, 32, true><<<N, 64, 0, stream>>>(Hb16, as_, ad_, row_start, csr_src, b1,
                                                hpen, N);

  // ---- layer 2: 256 -> 128, 1 head, no relu (alpha fused via atomics) ----
  zero_f32_kernel<<<(2 * N + 255) / 256, 256, 0, stream>>>(as_, 2 * N);  // as_[0..N) + spill into ad_? no:
  // as_ has N*8 capacity; zero first N of as_ and first N of ad_ separately is cheaper as one
  // kernel over the as_ region only if ad_ adjacent. They are adjacent allocations (N*8*4 each,
  // 256B-aligned) -> zero both explicitly:
  zero_f32_kernel<<<(N + 255) / 256, 256, 0, stream>>>(ad_, N);
  gemm_mfma<false, true><<<grid2, 256, 0, stream>>>(hpen, W2h, W2l, asr2, adt2, as_, ad_,
                                                    Hb16, N, OUTC, HID, 2);
  agg_kernel<1, 128, false><<<N, 64, 0, stream>>>(Hb16, as_, ad_, row_start, csr_src, b2,
                                                  out2, N);
}

// Round 21
// 223.141 us; speedup vs baseline: 1.1505x; 1.0016x over previous
//
#include <hip/hip_runtime.h>
#include <hip/hip_bf16.h>

// d_out is FLOAT32. h_pen = first N*256 f32, h = next N*128 f32.

using bf16 = __hip_bfloat16;

typedef __attribute__((ext_vector_type(8))) short bf16x8;
typedef __attribute__((ext_vector_type(4))) short short4v;
typedef __attribute__((ext_vector_type(4))) float f32x4;
typedef __attribute__((ext_vector_type(2))) float f32x2;
typedef __attribute__((ext_vector_type(2))) unsigned int uint2v;

__device__ __forceinline__ float u2f(unsigned u) { union { float f; unsigned u; } c; c.u = u; return c.f; }
__device__ __forceinline__ unsigned f2u(float x) { union { float f; unsigned u; } c; c.f = x; return c.u; }
__device__ __forceinline__ short bfbits(float x) {
  unsigned xu = f2u(x);
  return (short)((xu + 0x7FFF + ((xu >> 16) & 1)) >> 16);
}

// ============================ CSR build (dst-sorted) ============================
__global__ void hist_kernel(const int* __restrict__ ei, int E, int N, int* __restrict__ cnt) {
  int e = blockIdx.x * 256 + threadIdx.x;
  if (e >= E + N) return;
  int dst = (e < E) ? ei[E + e] : (e - E);
  atomicAdd(&cnt[dst], 1);
}

__global__ __launch_bounds__(1024) void scan_kernel(const int* __restrict__ cnt,
                                                    int* __restrict__ row_start, int N) {
  __shared__ int part[1024];
  int t = threadIdx.x;
  int chunk = (N + 1023) / 1024;
  int lo = t * chunk; if (lo > N) lo = N;
  int hi = lo + chunk; if (hi > N) hi = N;
  int s = 0;
  for (int i = lo; i < hi; ++i) s += cnt[i];
  part[t] = s;
  __syncthreads();
  for (int off = 1; off < 1024; off <<= 1) {
    int add = (t >= off) ? part[t - off] : 0;
    __syncthreads();
    part[t] += add;
    __syncthreads();
  }
  int run = part[t] - s;
  for (int i = lo; i < hi; ++i) { row_start[i] = run; run += cnt[i]; }
  if (t == 1023) row_start[N] = part[1023];
}

__global__ void scatter_kernel(const int* __restrict__ ei, int E, int N,
                               const int* __restrict__ row_start, int* __restrict__ cursor,
                               int* __restrict__ csr_src) {
  int e = blockIdx.x * 256 + threadIdx.x;
  if (e >= E + N) return;
  int src, dst;
  if (e < E) { src = ei[e]; dst = ei[E + e]; }
  else       { src = e - E; dst = e - E; }
  int pos = atomicAdd(&cursor[dst], 1);
  csr_src[row_start[dst] + pos] = src;
}

// ============================ weight presplit (row-major hi/lo) ============================
__global__ void split3_kernel(const float* __restrict__ W0, const float* __restrict__ W1,
                              const float* __restrict__ W2,
                              unsigned short* __restrict__ W0h, unsigned short* __restrict__ W0l,
                              unsigned short* __restrict__ W1h, unsigned short* __restrict__ W1l,
                              unsigned short* __restrict__ W2h, unsigned short* __restrict__ W2l,
                              int n0_4, int n1_4, int n2_4) {
  int i = blockIdx.x * 256 + threadIdx.x;
  const float* in; unsigned short *hi, *lo; int idx;
  if (i < n0_4)                { in = W0; hi = W0h; lo = W0l; idx = i; }
  else if (i < n0_4 + n1_4)    { in = W1; hi = W1h; lo = W1l; idx = i - n0_4; }
  else if (i < n0_4 + n1_4 + n2_4) { in = W2; hi = W2h; lo = W2l; idx = i - n0_4 - n1_4; }
  else return;
  f32x4 v = *(const f32x4*)(in + (size_t)idx * 4);
  short4v h, l;
#pragma unroll
  for (int k = 0; k < 4; ++k) {
    short hb = bfbits(v[k]);
    h[k] = hb;
    l[k] = bfbits(v[k] - u2f(((unsigned)(unsigned short)hb) << 16));
  }
  *(short4v*)(hi + (size_t)idx * 4) = h;
  *(short4v*)(lo + (size_t)idx * 4) = l;
}

// ============================ W -> MFMA fragment order ============================
// Wf[((jb*ktmax + kt32)*64 + lane)*8 + e]: lane (g=lane>>4, lr=lane&15), col=jb*16+lr,
// e<4 -> k=kt32*32+g*4+e ; e>=4 -> k=kt32*32+16+g*4+(e-4). Replicates make_frag exactly.
__global__ void prefrag_kernel(const unsigned short* __restrict__ Wh0, const unsigned short* __restrict__ Wl0,
                               const unsigned short* __restrict__ Wh1, const unsigned short* __restrict__ Wl1,
                               const unsigned short* __restrict__ Wh2, const unsigned short* __restrict__ Wl2,
                               unsigned short* __restrict__ F0h, unsigned short* __restrict__ F0l,
                               unsigned short* __restrict__ F1h, unsigned short* __restrict__ F1l,
                               unsigned short* __restrict__ F2h, unsigned short* __restrict__ F2l,
                               int c0, int c1, int c2) {   // c = (Nn/16)*(K/32)*64 per weight
  int id = blockIdx.x * 256 + threadIdx.x;
  const unsigned short *Wh, *Wl; unsigned short *Fh, *Fl; int K, ktmax, rid;
  if (id < c0)            { Wh = Wh0; Wl = Wl0; Fh = F0h; Fl = F0l; K = 512; ktmax = 16; rid = id; }
  else if (id < c0 + c1)  { Wh = Wh1; Wl = Wl1; Fh = F1h; Fl = F1l; K = 256; ktmax = 8;  rid = id - c0; }
  else if (id < c0 + c1 + c2) { Wh = Wh2; Wl = Wl2; Fh = F2h; Fl = F2l; K = 256; ktmax = 8; rid = id - c0 - c1; }
  else return;
  int lane = rid & 63;
  int blk  = rid >> 6;              // jb*ktmax + kt32
  int jb   = blk / ktmax;
  int kt32 = blk % ktmax;
  int lr = lane & 15, g = lane >> 4;
  int col = jb * 16 + lr;
  const unsigned short* sh = Wh + (size_t)col * K + kt32 * 32;
  const unsigned short* sl = Wl + (size_t)col * K + kt32 * 32;
  short4v h0, h1, l0, l1;
#pragma unroll
  for (int e = 0; e < 4; ++e) {
    h0[e] = sh[g * 4 + e];      h1[e] = sh[16 + g * 4 + e];
    l0[e] = sl[g * 4 + e];      l1[e] = sl[16 + g * 4 + e];
  }
  size_t o = ((size_t)blk * 64 + lane) * 8;
  *(short4v*)(Fh + o)     = h0;
  *(short4v*)(Fh + o + 4) = h1;
  *(short4v*)(Fl + o)     = l0;
  *(short4v*)(Fl + o + 4) = l1;
}

__global__ void zero2_f32_kernel(float* __restrict__ a, float* __restrict__ b, int n) {
  int i = blockIdx.x * 256 + threadIdx.x;
  if (i < n) a[i] = 0.f;
  else if (i < 2 * n) b[i - n] = 0.f;
}

// ============================ MFMA GEMM 64x64: A via LDS, B direct from fragment-ordered global ============================
#define LDP 40  // LDS pitch in shorts

__device__ __forceinline__ bf16x8 make_frag(const short* S, int row, int g) {
  short4v klo = *(const short4v*)&S[row * LDP + g * 4];
  short4v khi = *(const short4v*)&S[row * LDP + 16 + g * 4];
  bf16x8 r;
#pragma unroll
  for (int i = 0; i < 4; ++i) { r[i] = klo[i]; r[i + 4] = khi[i]; }
  return r;
}

template <bool FUSE8, bool FUSE1>
__global__ __launch_bounds__(256) void gemm_mfma(const float* __restrict__ Af,
                                                 const unsigned short* __restrict__ Fh,
                                                 const unsigned short* __restrict__ Fl,
                                                 const float* __restrict__ Asrc,
                                                 const float* __restrict__ Adst,
                                                 float* __restrict__ as_,
                                                 float* __restrict__ ad_,
                                                 unsigned short* __restrict__ C16,
                                                 int M, int Nn, int K, int NB) {
  // XCD-aware: same-bm blocks differ by 8 in id -> same XCD -> A panel L2 reuse.
  int id = blockIdx.x;
  int r8 = id & 7;
  int q  = id >> 3;
  int bn = q % NB;
  int bm = r8 + 8 * (q / NB);
  if (bm * 64 >= M) return;

  __shared__ short Ah[64 * LDP];
  __shared__ short Al[64 * LDP];
  int t = threadIdx.x;
  int w = t >> 6, l = t & 63;
  int g = l >> 4, lr = l & 15;
  int ktmax = K >> 5;

  f32x4 acc[4];
#pragma unroll
  for (int j = 0; j < 4; ++j) acc[j] = (f32x4)(0.f);

  int srow = t >> 2;            // 0..63
  int sseg = (t & 3) * 8;       // 0,8,16,24
  int gm = bm * 64 + srow;
  const float* Abase = Af + (size_t)gm * K + sseg;
  // B fragment base for this lane: Fh[((jb*ktmax + kt32)*64 + l)*8]
  const unsigned short* FhL = Fh + (size_t)l * 8;
  const unsigned short* FlL = Fl + (size_t)l * 8;

  // ---- prologue: A iteration 0 ----
  f32x4 va0 = (f32x4)(0.f), va1 = (f32x4)(0.f);
  if (gm < M) { va0 = *(const f32x4*)(Abase); va1 = *(const f32x4*)(Abase + 4); }

  for (int kt32 = 0; kt32 < ktmax; ++kt32) {
    short4v h0, l0, h1, l1;
#pragma unroll
    for (int i = 0; i < 4; ++i) {
      short hb0 = bfbits(va0[i]);
      l0[i] = bfbits(va0[i] - u2f(((unsigned)(unsigned short)hb0) << 16));
      h0[i] = hb0;
      short hb1 = bfbits(va1[i]);
      l1[i] = bfbits(va1[i] - u2f(((unsigned)(unsigned short)hb1) << 16));
      h1[i] = hb1;
    }
    __syncthreads();
    *(short4v*)&Ah[srow * LDP + sseg]     = h0;
    *(short4v*)&Ah[srow * LDP + sseg + 4] = h1;
    *(short4v*)&Al[srow * LDP + sseg]     = l0;
    *(short4v*)&Al[srow * LDP + sseg + 4] = l1;
    __syncthreads();

    // ---- prefetch next A tile (overlaps MFMA + B loads) ----
    if (kt32 + 1 < ktmax) {
      int k2 = (kt32 + 1) << 5;
      if (gm < M) { va0 = *(const f32x4*)(Abase + k2); va1 = *(const f32x4*)(Abase + k2 + 4); }
    }

    int arow = w * 16 + lr;
    bf16x8 ah = make_frag(Ah, arow, g);
    bf16x8 al = make_frag(Al, arow, g);
#pragma unroll
    for (int j = 0; j < 4; ++j) {
      size_t fo = ((size_t)((bn * 4 + j) * ktmax + kt32) * 64) * 8;
      bf16x8 bh = *(const bf16x8*)(FhL + fo);
      bf16x8 bl = *(const bf16x8*)(FlL + fo);
      acc[j] = __builtin_amdgcn_mfma_f32_16x16x32_bf16(ah, bh, acc[j], 0, 0, 0);
      acc[j] = __builtin_amdgcn_mfma_f32_16x16x32_bf16(al, bh, acc[j], 0, 0, 0);
      acc[j] = __builtin_amdgcn_mfma_f32_16x16x32_bf16(ah, bl, acc[j], 0, 0, 0);
    }
  }

  // ---- C16 write. C/D layout (HW-verified m89): col = lane&15, row = (lane>>4)*4 + reg ----
  // NOTE: within this block, columns covered are bn*64 + j*16 + lr.
#pragma unroll
  for (int j = 0; j < 4; ++j) {
#pragma unroll
    for (int r = 0; r < 4; ++r) {
      int row = bm * 64 + w * 16 + g * 4 + r;
      int col = bn * 64 + j * 16 + lr;
      if (row < M) C16[(size_t)row * Nn + col] = (unsigned short)bfbits(acc[j][r]);
    }
  }

  // ---- fused alpha (H=8): block covers heads 2bn, 2bn+1 ----
  if constexpr (FUSE8) {
    float cs[4], cd[4];
#pragma unroll
    for (int j = 0; j < 4; ++j) {
      cs[j] = Asrc[bn * 64 + j * 16 + lr];
      cd[j] = Adst[bn * 64 + j * 16 + lr];
    }
#pragma unroll
    for (int r = 0; r < 4; ++r) {
      float sA0 = acc[0][r] * cs[0] + acc[1][r] * cs[1];
      float sA1 = acc[2][r] * cs[2] + acc[3][r] * cs[3];
      float sD0 = acc[0][r] * cd[0] + acc[1][r] * cd[1];
      float sD1 = acc[2][r] * cd[2] + acc[3][r] * cd[3];
#pragma unroll
      for (int mask = 1; mask < 16; mask <<= 1) {
        sA0 += __shfl_xor(sA0, mask);
        sA1 += __shfl_xor(sA1, mask);
        sD0 += __shfl_xor(sD0, mask);
        sD1 += __shfl_xor(sD1, mask);
      }
      if (lr == 0) {
        int row = bm * 64 + w * 16 + g * 4 + r;
        if (row < M) {
          as_[row * 8 + bn * 2]     = sA0;
          as_[row * 8 + bn * 2 + 1] = sA1;
          ad_[row * 8 + bn * 2]     = sD0;
          ad_[row * 8 + bn * 2 + 1] = sD1;
        }
      }
    }
  }

  // ---- fused alpha (H=1, C=128): partial 64-col dot, atomicAdd (pre-zeroed) ----
  if constexpr (FUSE1) {
    float cs[4], cd[4];
#pragma unroll
    for (int j = 0; j < 4; ++j) {
      cs[j] = Asrc[bn * 64 + j * 16 + lr];
      cd[j] = Adst[bn * 64 + j * 16 + lr];
    }
#pragma unroll
    for (int r = 0; r < 4; ++r) {
      float sA = acc[0][r] * cs[0] + acc[1][r] * cs[1] + acc[2][r] * cs[2] + acc[3][r] * cs[3];
      float sD = acc[0][r] * cd[0] + acc[1][r] * cd[1] + acc[2][r] * cd[2] + acc[3][r] * cd[3];
#pragma unroll
      for (int mask = 1; mask < 16; mask <<= 1) {
        sA += __shfl_xor(sA, mask);
        sD += __shfl_xor(sD, mask);
      }
      if (lr == 0) {
        int row = bm * 64 + w * 16 + g * 4 + r;
        if (row < M) {
          atomicAdd(&as_[row], sA);
          atomicAdd(&ad_[row], sD);
        }
      }
    }
  }
}

// ============================ softmax + aggregate (bf16 gather, 4-deep) ============================
template <int H, int C, bool RELU>
__global__ __launch_bounds__(64) void agg_kernel(const unsigned short* __restrict__ Hb16,
                                                 const float* __restrict__ as_,
                                                 const float* __restrict__ ad_,
                                                 const int* __restrict__ row_start,
                                                 const int* __restrict__ csr_src,
                                                 const float* __restrict__ bias,
                                                 float* __restrict__ out, int N) {
  int n = blockIdx.x;
  if (n >= N) return;
  int l = threadIdx.x;
  int s = row_start[n], e = row_start[n + 1];

  constexpr int LPH = 64 / H;
  constexpr int CPL = C / LPH;
  constexpr int HC = H * C;
  int h2 = l / LPH;
  int cb = (l % LPH) * CPL;
  float ad2 = ad_[n * H + h2];

  float acc[CPL];
#pragma unroll
  for (int c = 0; c < CPL; ++c) acc[c] = 0.f;
  float denom = 0.f;

  auto lrelu = [](float x) { return x > 0.f ? x : 0.2f * x; };

  int j = s;
  for (; j + 3 < e; j += 4) {
    int s0 = csr_src[j], s1 = csr_src[j + 1], s2 = csr_src[j + 2], s3 = csr_src[j + 3];
    float x0 = as_[s0 * H + h2], x1 = as_[s1 * H + h2];
    float x2 = as_[s2 * H + h2], x3 = as_[s3 * H + h2];
    const unsigned short* hp0 = Hb16 + (size_t)s0 * HC + h2 * C + cb;
    const unsigned short* hp1 = Hb16 + (size_t)s1 * HC + h2 * C + cb;
    const unsigned short* hp2 = Hb16 + (size_t)s2 * HC + h2 * C + cb;
    const unsigned short* hp3 = Hb16 + (size_t)s3 * HC + h2 * C + cb;
    float p0 = __expf(lrelu(x0 + ad2)), p1 = __expf(lrelu(x1 + ad2));
    float p2 = __expf(lrelu(x2 + ad2)), p3 = __expf(lrelu(x3 + ad2));
    denom += (p0 + p1) + (p2 + p3);
    if constexpr (CPL == 4) {
      uint2v u0 = *(const uint2v*)hp0;
      uint2v u1 = *(const uint2v*)hp1;
      uint2v u2 = *(const uint2v*)hp2;
      uint2v u3 = *(const uint2v*)hp3;
#pragma unroll
      for (int c = 0; c < 2; ++c) {
        acc[2 * c]     += p0 * u2f(u0[c] << 16)         + p1 * u2f(u1[c] << 16)
                        + p2 * u2f(u2[c] << 16)         + p3 * u2f(u3[c] << 16);
        acc[2 * c + 1] += p0 * u2f(u0[c] & 0xFFFF0000u) + p1 * u2f(u1[c] & 0xFFFF0000u)
                        + p2 * u2f(u2[c] & 0xFFFF0000u) + p3 * u2f(u3[c] & 0xFFFF0000u);
      }
    } else {
      unsigned u0 = *(const unsigned*)hp0;
      unsigned u1 = *(const unsigned*)hp1;
      unsigned u2 = *(const unsigned*)hp2;
      unsigned u3 = *(const unsigned*)hp3;
      acc[0] += p0 * u2f(u0 << 16)         + p1 * u2f(u1 << 16)
              + p2 * u2f(u2 << 16)         + p3 * u2f(u3 << 16);
      acc[1] += p0 * u2f(u0 & 0xFFFF0000u) + p1 * u2f(u1 & 0xFFFF0000u)
              + p2 * u2f(u2 & 0xFFFF0000u) + p3 * u2f(u3 & 0xFFFF0000u);
    }
  }
  for (; j < e; ++j) {
    int s0 = csr_src[j];
    float p0 = __expf(lrelu(as_[s0 * H + h2] + ad2));
    denom += p0;
    const unsigned short* hp0 = Hb16 + (size_t)s0 * HC + h2 * C + cb;
    if constexpr (CPL == 4) {
      uint2v u0 = *(const uint2v*)hp0;
#pragma unroll
      for (int c = 0; c < 2; ++c) {
        acc[2 * c]     += p0 * u2f(u0[c] << 16);
        acc[2 * c + 1] += p0 * u2f(u0[c] & 0xFFFF0000u);
      }
    } else {
      unsigned u0 = *(const unsigned*)hp0;
      acc[0] += p0 * u2f(u0 << 16);
      acc[1] += p0 * u2f(u0 & 0xFFFF0000u);
    }
  }

  float inv = 1.f / (denom + 1e-16f);
#pragma unroll
  for (int c = 0; c < CPL; ++c) {
    float v = acc[c] * inv + bias[h2 * C + cb + c];
    if (RELU) v = fmaxf(v, 0.f);
    out[(size_t)n * HC + h2 * C + cb + c] = v;
  }
}

// ============================ launch ============================
extern "C" void kernel_launch(void* const* d_in, const int* in_sizes, int n_in,
                              void* d_out, int out_size, void* d_ws, size_t ws_size,
                              hipStream_t stream) {
  const float* x    = (const float*)d_in[0];
  const int*   ei   = (const int*)d_in[1];
  const float* W0   = (const float*)d_in[2];
  const float* asr0 = (const float*)d_in[3];
  const float* adt0 = (const float*)d_in[4];
  const float* b0   = (const float*)d_in[5];
  const float* W1   = (const float*)d_in[6];
  const float* asr1 = (const float*)d_in[7];
  const float* adt1 = (const float*)d_in[8];
  const float* b1   = (const float*)d_in[9];
  const float* W2   = (const float*)d_in[10];
  const float* asr2 = (const float*)d_in[11];
  const float* adt2 = (const float*)d_in[12];
  const float* b2   = (const float*)d_in[13];

  const int FIN = 512, HID = 256, OUTC = 128;
  int N = in_sizes[0] / FIN;          // 20000
  int E = in_sizes[1] / 2;            // 320000
  int Etot = E + N;

  char* ws = (char*)d_ws;
  size_t off = 0;
  auto alloc = [&](size_t bytes) -> void* {
    void* p = ws + off;
    off = (off + bytes + 255) & ~(size_t)255;
    return p;
  };
  int* cnt       = (int*)alloc((size_t)N * 4);
  int* cursor    = (int*)alloc((size_t)N * 4);
  int* row_start = (int*)alloc((size_t)(N + 1) * 4);
  int* csr_src   = (int*)alloc((size_t)Etot * 4);
  float* as_     = (float*)alloc((size_t)N * 8 * 4);
  float* ad_     = (float*)alloc((size_t)N * 8 * 4);
  unsigned short* Hb16 = (unsigned short*)alloc((size_t)N * HID * 2);   // bf16 C mirror
  float* act     = (float*)alloc((size_t)N * HID * 4);                  // layer activation f32
  // row-major presplit (intermediate)
  unsigned short* W0h = (unsigned short*)alloc((size_t)HID * FIN * 2);
  unsigned short* W0l = (unsigned short*)alloc((size_t)HID * FIN * 2);
  unsigned short* W1h = (unsigned short*)alloc((size_t)HID * HID * 2);
  unsigned short* W1l = (unsigned short*)alloc((size_t)HID * HID * 2);
  unsigned short* W2h = (unsigned short*)alloc((size_t)OUTC * HID * 2);
  unsigned short* W2l = (unsigned short*)alloc((size_t)OUTC * HID * 2);
  // fragment-ordered
  unsigned short* F0h = (unsigned short*)alloc((size_t)HID * FIN * 2);
  unsigned short* F0l = (unsigned short*)alloc((size_t)HID * FIN * 2);
  unsigned short* F1h = (unsigned short*)alloc((size_t)HID * HID * 2);
  unsigned short* F1l = (unsigned short*)alloc((size_t)HID * HID * 2);
  unsigned short* F2h = (unsigned short*)alloc((size_t)OUTC * HID * 2);
  unsigned short* F2l = (unsigned short*)alloc((size_t)OUTC * HID * 2);

  float* hpen = (float*)d_out;                       // [N, 256] f32
  float* out2 = (float*)d_out + (size_t)N * HID;     // [N, 128] f32

  // ---- presplit + prefragment weights ----
  int n0_4 = HID * FIN / 4, n1_4 = HID * HID / 4, n2_4 = OUTC * HID / 4;
  int nsplit = n0_4 + n1_4 + n2_4;
  split3_kernel<<<(nsplit + 255) / 256, 256, 0, stream>>>(W0, W1, W2, W0h, W0l, W1h, W1l,
                                                          W2h, W2l, n0_4, n1_4, n2_4);
  int c0 = (HID / 16) * (FIN / 32) * 64;   // 16*16*64
  int c1 = (HID / 16) * (HID / 32) * 64;   // 16*8*64
  int c2 = (OUTC / 16) * (HID / 32) * 64;  // 8*8*64
  prefrag_kernel<<<(c0 + c1 + c2 + 255) / 256, 256, 0, stream>>>(
      W0h, W0l, W1h, W1l, W2h, W2l, F0h, F0l, F1h, F1l, F2h, F2l, c0, c1, c2);

  // ---- CSR build ----
  (void)hipMemsetAsync(cnt, 0, (size_t)((char*)cursor - (char*)cnt) + (size_t)N * 4, stream);
  int eb = (Etot + 255) / 256;
  hist_kernel<<<eb, 256, 0, stream>>>(ei, E, N, cnt);
  scan_kernel<<<1, 1024, 0, stream>>>(cnt, row_start, N);
  scatter_kernel<<<eb, 256, 0, stream>>>(ei, E, N, row_start, cursor, csr_src);

  int mb = (N + 63) / 64;          // 313
  int mb8 = (mb + 7) / 8;          // 40
  int grid4 = 8 * 4 * mb8;         // NB=4 (HID=256)
  int grid2 = 8 * 2 * mb8;         // NB=2 (OUTC=128)

  // ---- layer 0: 512 -> 8x32, relu (alpha fused) ----
  gemm_mfma<true, false><<<grid4, 256, 0, stream>>>(x, F0h, F0l, asr0, adt0, as_, ad_,
                                                    Hb16, N, HID, FIN, 4);
  agg_kernel<8, 32, true><<<N, 64, 0, stream>>>(Hb16, as_, ad_, row_start, csr_src, b0,
                                                act, N);

  // ---- layer 1: 256 -> 8x32, relu (alpha fused; h_pen -> d_out f32) ----
  gemm_mfma<true, false><<<grid4, 256, 0, stream>>>(act, F1h, F1l, asr1, adt1, as_, ad_,
                                                    Hb16, N, HID, HID, 4);
  agg_kernel<8, 32, true><<<N, 64, 0, stream>>>(Hb16, as_, ad_, row_start, csr_src, b1,
                                                hpen, N);

  // ---- layer 2: 256 -> 128, 1 head, no relu (alpha fused via atomics) ----
  zero2_f32_kernel<<<(2 * N + 255) / 256, 256, 0, stream>>>(as_, ad_, N);
  gemm_mfma<false, true><<<grid2, 256, 0, stream>>>(hpen, F2h, F2l, asr2, adt2, as_, ad_,
                                                    Hb16, N, OUTC, HID, 2);
  agg_kernel<1, 128, false><<<N, 64, 0, stream>>>(Hb16, as_, ad_, row_start, csr_src, b2,
                                                  out2, N);
}